// Round 9
// baseline (160.955 us; speedup 1.0000x reference)
//
#include <hip/hip_runtime.h>

typedef unsigned short u16;
typedef __bf16 bf16x8 __attribute__((ext_vector_type(8)));
typedef float f32x4 __attribute__((ext_vector_type(4)));

__device__ __forceinline__ u16 f2bf(float f) {
  unsigned int u = __float_as_uint(f);
  u += 0x7fffu + ((u >> 16) & 1u);
  return (u16)(u >> 16);
}
__device__ __forceinline__ float bf2f(u16 v) {
  return __uint_as_float(((unsigned)v) << 16);
}

#define GLDS16(gp, lp)                                                   \
  __builtin_amdgcn_global_load_lds(                                      \
      (const __attribute__((address_space(1))) unsigned int*)(gp),       \
      (__attribute__((address_space(3))) unsigned int*)(lp), 16, 0, 0)

// B=8, C=256, L=4096, M=32768, NHEAD=8, dim=32
// ws layout (bytes)
#define OFF_WQ     0u
#define OFF_WK     131072u     /* wkvt rows 0:256 */
#define OFF_WV     262144u
#define OFF_WM     393216u
#define OFF_W1     524288u
#define OFF_W2     1048576u
#define OFF_CAT    1310720u    /* u16 [M][512]: 0:256 xs, 256:512 ln1 */
#define OFF_SSB    34865152u   /* u16 [M][256] ss_bf16 */
#define OFF_KVPROJ 68419584u   /* u16 [M][512] K|vals bf16 ; later hidden */
#define OFF_KS     152567808u  /* f32 [64][32] Ksum */
#define OFF_KVP    152576000u  /* f32 [8][64][32][32] partials */
#define OFF_KSP    154673152u  /* f32 [8][64][32] partials */
#define OFF_WC     154740736u  /* u16 [8][256][256] wcomb */

// ---- transpose fp32 [C,L] -> bf16 [L,C], 64x64 tiles, uint4 writes ----------
__global__ __launch_bounds__(256) void transpose_in_kernel(
    const float* __restrict__ x, const float* __restrict__ srcp,
    u16* __restrict__ cat, u16* __restrict__ ssb) {
  __shared__ float s[64][65];
  const int z = blockIdx.z;
  const float* src = z < 8 ? x : srcp;
  u16* dst = z < 8 ? cat : ssb;
  const int dstride = z < 8 ? 512 : 256;
  const int b = z & 7;
  const int lt = blockIdx.x * 64, ct = blockIdx.y * 64;
  const int t = threadIdx.x;
  const int cl = t >> 2, loff = (t & 3) * 16;
#pragma unroll
  for (int j = 0; j < 4; ++j) {
    float4 v = *reinterpret_cast<const float4*>(
        src + ((size_t)b * 256 + ct + cl) * 4096 + lt + loff + j * 4);
    s[cl][loff + j * 4 + 0] = v.x;
    s[cl][loff + j * 4 + 1] = v.y;
    s[cl][loff + j * 4 + 2] = v.z;
    s[cl][loff + j * 4 + 3] = v.w;
  }
  __syncthreads();
#pragma unroll
  for (int i = 0; i < 2; ++i) {
    int id = t + i * 256;          // 0..511
    int ll = id >> 3, cg = id & 7;
    unsigned pk[4];
#pragma unroll
    for (int j = 0; j < 4; ++j) {
      unsigned lo = f2bf(s[cg * 8 + j * 2][ll]);
      unsigned hi = f2bf(s[cg * 8 + j * 2 + 1][ll]);
      pk[j] = lo | (hi << 16);
    }
    uint4 val = {pk[0], pk[1], pk[2], pk[3]};
    *reinterpret_cast<uint4*>(
        dst + ((size_t)b * 4096 + lt + ll) * dstride + ct + cg * 8) = val;
  }
}

// ---- weight prep: fp32 [K,N] -> bf16 [N,K], all weights one dispatch --------
__global__ __launch_bounds__(256) void wprep_all_kernel(
    const float* __restrict__ Wq, const float* __restrict__ Wk,
    const float* __restrict__ Wv, const float* __restrict__ Wm,
    const float* __restrict__ W1, const float* __restrict__ W2,
    u16* __restrict__ dq, u16* __restrict__ dk, u16* __restrict__ dv,
    u16* __restrict__ dm, u16* __restrict__ d1, u16* __restrict__ d2) {
  __shared__ float s[32][33];
  int bid = blockIdx.x;
  const float* src; u16* dst; int Kd, Nd, t;
  if (bid < 64)       { src = Wq; dst = dq; Kd = 256; Nd = 256; t = bid; }
  else if (bid < 128) { src = Wk; dst = dk; Kd = 256; Nd = 256; t = bid - 64; }
  else if (bid < 192) { src = Wv; dst = dv; Kd = 256; Nd = 256; t = bid - 128; }
  else if (bid < 256) { src = Wm; dst = dm; Kd = 256; Nd = 256; t = bid - 192; }
  else if (bid < 512) { src = W1; dst = d1; Kd = 512; Nd = 512; t = bid - 256; }
  else                { src = W2; dst = d2; Kd = 512; Nd = 256; t = bid - 512; }
  int ntn = Nd >> 5;
  int kt = (t / ntn) * 32, nt = (t % ntn) * 32;
  int tx = threadIdx.x & 31, ty = threadIdx.x >> 5;
#pragma unroll
  for (int i = 0; i < 4; ++i)
    s[ty + i * 8][tx] = src[(size_t)(kt + ty + i * 8) * Nd + nt + tx];
  __syncthreads();
#pragma unroll
  for (int i = 0; i < 4; ++i)
    dst[(size_t)(nt + ty + i * 8) * Kd + kt + tx] = f2bf(s[tx][ty + i * 8]);
}

// ---- bf16 MFMA GEMM, 128x256 tile, 8 waves (2m x 4n), gload_lds staging -----
// Grid 512 linear, XCD-chunked. EPI: 3 relu bf16 | 4 fused kv bf16
template <int EPI>
__global__ __launch_bounds__(512) void gemm256_kernel(
    const u16* __restrict__ A, int lda, const u16* __restrict__ Wt, int K,
    u16* __restrict__ outp, int ldo) {
  __shared__ alignas(16) u16 sA[128 * 64];
  __shared__ alignas(16) u16 sB[256 * 64];
  const int t = threadIdx.x;
  int bid = blockIdx.x;
  int xcd = bid & 7, i0 = bid >> 3;
  const int m0 = (xcd * 32 + (i0 >> 1)) * 128;
  const int n0 = (i0 & 1) * 256;
  const int w = t >> 6, lane = t & 63;
  const int wm = (w >> 2) * 64, wn = (w & 3) * 64;
  const int lr = lane & 15, lk = lane >> 4;
  f32x4 acc[4][4] = {};
  const int nkt = K >> 6;
  for (int kt = 0; kt < nkt; ++kt) {
    __syncthreads();
#pragma unroll
    for (int i = 0; i < 2; ++i) {
      int id = t + i * 512, row = id >> 3, ch = (id & 7) << 3;
      GLDS16(A + (size_t)(m0 + row) * lda + kt * 64 + ch, sA + id * 8);
    }
#pragma unroll
    for (int i = 0; i < 4; ++i) {
      int id = t + i * 512, row = id >> 3, ch = (id & 7) << 3;
      GLDS16(Wt + (size_t)(n0 + row) * K + kt * 64 + ch, sB + id * 8);
    }
    __syncthreads();
    bf16x8 af[4][2], bfr[4][2];
#pragma unroll
    for (int f = 0; f < 4; ++f) {
#pragma unroll
      for (int ks = 0; ks < 2; ++ks) {
        af[f][ks] = *reinterpret_cast<const bf16x8*>(
            &sA[(wm + f * 16 + lr) * 64 + ks * 32 + lk * 8]);
        bfr[f][ks] = *reinterpret_cast<const bf16x8*>(
            &sB[(wn + f * 16 + lr) * 64 + ks * 32 + lk * 8]);
      }
    }
#pragma unroll
    for (int ks = 0; ks < 2; ++ks)
#pragma unroll
      for (int fm = 0; fm < 4; ++fm)
#pragma unroll
        for (int fn = 0; fn < 4; ++fn)
          acc[fm][fn] = __builtin_amdgcn_mfma_f32_16x16x32_bf16(
              af[fm][ks], bfr[fn][ks], acc[fm][fn], 0, 0, 0);
  }
  const int r0 = (lane >> 4) * 4, c0 = lane & 15;
#pragma unroll
  for (int fm = 0; fm < 4; ++fm) {
#pragma unroll
    for (int fn = 0; fn < 4; ++fn) {
      int gr = m0 + wm + fm * 16 + r0;
      int gc = n0 + wn + fn * 16 + c0;
#pragma unroll
      for (int r = 0; r < 4; ++r) {
        float v = acc[fm][fn][r];
        if (EPI == 3) v = v > 0.f ? v : 0.f;
        if (EPI == 4) v = (gc < 256) ? (v > 0.f ? v + 1.f : __expf(v)) : v * (1.f / 4096.f);
        outp[(size_t)(gr + r) * ldo + gc] = f2bf(v);
      }
    }
  }
}

// ---- KV partial over L-slices (reads bf16 kvproj [M][512]) ------------------
// flat grid 512, b = id&7 -> consumer blocks land on the XCD that produced
// batch b's kvproj rows (kv gemm XCD-chunk maps m-panel 4096b.. to XCD b).
__global__ __launch_bounds__(256) void kv_partial_kernel(
    const u16* __restrict__ KVproj, float* __restrict__ KVp,
    float* __restrict__ KSp) {
  __shared__ alignas(16) float sK[64][32];
  __shared__ alignas(16) float sV[64][32];
  const int id = blockIdx.x;
  const int b = id & 7;
  const int h = (id >> 3) & 7, sl = id >> 6;
  const int t = threadIdx.x;
  const int lrow = t >> 2, lcol = (t & 3) * 8;
  const int d = t >> 3, vg = (t & 7) * 4;
  float a0 = 0, a1 = 0, a2 = 0, a3 = 0, ks = 0;
  for (int lt = 0; lt < 512; lt += 64) {
    __syncthreads();
    size_t roff = ((size_t)b * 4096 + sl * 512 + lt + lrow) * 512 + h * 32 + lcol;
    uint4 kq = *reinterpret_cast<const uint4*>(KVproj + roff);
    uint4 vq = *reinterpret_cast<const uint4*>(KVproj + roff + 256);
    float* dk = &sK[lrow][lcol];
    float* dv = &sV[lrow][lcol];
#pragma unroll
    for (int j = 0; j < 4; ++j) {
      unsigned uk = ((const unsigned*)&kq)[j];
      unsigned uv = ((const unsigned*)&vq)[j];
      dk[2 * j] = __uint_as_float(uk << 16);
      dk[2 * j + 1] = __uint_as_float(uk & 0xffff0000u);
      dv[2 * j] = __uint_as_float(uv << 16);
      dv[2 * j + 1] = __uint_as_float(uv & 0xffff0000u);
    }
    __syncthreads();
#pragma unroll 8
    for (int i = 0; i < 64; ++i) {
      float kd = sK[i][d];
      a0 += kd * sV[i][vg + 0];
      a1 += kd * sV[i][vg + 1];
      a2 += kd * sV[i][vg + 2];
      a3 += kd * sV[i][vg + 3];
      ks += kd;
    }
  }
  const int bh = b * 8 + h;
  float* o = KVp + (size_t)sl * 65536 + bh * 1024 + d * 32 + vg;
  o[0] = a0; o[1] = a1; o[2] = a2; o[3] = a3;
  if ((t & 7) == 0) KSp[(size_t)sl * 2048 + bh * 32 + d] = ks;
}

// ---- merged: reduce KVp -> KV[b] (LDS) ; Ksum ; wcomb chunk -----------------
__global__ __launch_bounds__(256) void kvred_wcomb_kernel(
    const float* __restrict__ KVp, const float* __restrict__ KSp,
    const u16* __restrict__ wmt, u16* __restrict__ wc,
    float* __restrict__ Ksum) {
  __shared__ float sKV[8 * 1032];
  const int b = blockIdx.x >> 3, nc = blockIdx.x & 7;
  const int t = threadIdx.x;
#pragma unroll
  for (int i = 0; i < 32; ++i) {
    int idx = t + i * 256;
    float s = 0.f;
#pragma unroll
    for (int sl = 0; sl < 8; ++sl) s += KVp[(size_t)sl * 65536 + b * 8192 + idx];
    sKV[(idx >> 10) * 1032 + (idx & 1023)] = s;
  }
  if (nc == 0) {
    float s = 0.f;
#pragma unroll
    for (int sl = 0; sl < 8; ++sl) s += KSp[(size_t)sl * 2048 + b * 256 + t];
    Ksum[b * 256 + t] = s;
  }
  __syncthreads();
  const int n = nc * 32 + (t >> 3), h = t & 7;
  float wmv[32];
  const u16* wmrow = wmt + (size_t)n * 256 + h * 32;
#pragma unroll
  for (int v = 0; v < 32; ++v) wmv[v] = bf2f(wmrow[v]);
  unsigned pk[16];
  const float* kvh = &sKV[h * 1032];
#pragma unroll
  for (int dp = 0; dp < 16; ++dp) {
    unsigned lohi[2];
#pragma unroll
    for (int e = 0; e < 2; ++e) {
      int d = dp * 2 + e;
      const float* kv = kvh + d * 32;
      float s = 0.f;
#pragma unroll
      for (int v = 0; v < 32; ++v) s += kv[v] * wmv[v];
      lohi[e] = f2bf(s);
    }
    pk[dp] = lohi[0] | (lohi[1] << 16);
  }
  uint4* dst = (uint4*)(wc + ((size_t)b * 256 + n) * 256 + h * 32);
#pragma unroll
  for (int j = 0; j < 4; ++j) {
    uint4 val = {pk[j * 4], pk[j * 4 + 1], pk[j * 4 + 2], pk[j * 4 + 3]};
    dst[j] = val;
  }
}

// ---- FUSED: Qproj + elu+1 + z-scale + (Qs @ Wcomb) + LN1 -> cat[:,256:512] --
// BM=128, 512 threads (8 waves 2m x 4n), grid 256.
// Phase 2 reads Wcomb fragments DIRECT from global (128KB/batch, L2-hot) —
// no LDS staging, 4 barriers total instead of ~20.
__global__ __launch_bounds__(512) void qmsg_kernel(
    const u16* __restrict__ cat, const u16* __restrict__ WqT,
    const float* __restrict__ KSb, const u16* __restrict__ wc,
    const float* __restrict__ g1, const float* __restrict__ b1,
    u16* __restrict__ catout) {
  __shared__ alignas(16) char smem[53248];
  u16* sA = (u16*)smem;                  // phase1 [128][64]
  u16* sB = (u16*)(smem + 16384);        // phase1 [256][64]
  u16* Qlds = (u16*)smem;                // phase2 overlay [128][136]
  float* scr = (float*)(smem + 49152);   // [128][8]
  const int t = threadIdx.x;
  const int m0 = blockIdx.x * 128;
  const int b = m0 >> 12;
  const int w = t >> 6, lane = t & 63;
  const int wm = (w >> 2) * 64, wn = (w & 3) * 64;
  const int lr = lane & 15, lk = lane >> 4;
  f32x4 acc[4][4] = {};
  float ksv[4];
#pragma unroll
  for (int fn = 0; fn < 4; ++fn) ksv[fn] = KSb[b * 256 + wn + fn * 16 + lr];
  // ---- phase 1: Q-proj GEMM (K=256) ----
  for (int kt = 0; kt < 4; ++kt) {
    __syncthreads();
#pragma unroll
    for (int i = 0; i < 2; ++i) {
      int id = t + i * 512, row = id >> 3, ch = (id & 7) << 3;
      GLDS16(cat + (size_t)(m0 + row) * 512 + kt * 64 + ch, sA + id * 8);
    }
#pragma unroll
    for (int i = 0; i < 4; ++i) {
      int id = t + i * 512, row = id >> 3, ch = (id & 7) << 3;
      GLDS16(WqT + (size_t)row * 256 + kt * 64 + ch, sB + id * 8);
    }
    __syncthreads();
    bf16x8 af[4][2], bfr[4][2];
#pragma unroll
    for (int f = 0; f < 4; ++f)
#pragma unroll
      for (int ks = 0; ks < 2; ++ks) {
        af[f][ks] = *(const bf16x8*)&sA[(wm + f * 16 + lr) * 64 + ks * 32 + lk * 8];
        bfr[f][ks] = *(const bf16x8*)&sB[(wn + f * 16 + lr) * 64 + ks * 32 + lk * 8];
      }
#pragma unroll
    for (int ks = 0; ks < 2; ++ks)
#pragma unroll
      for (int fm = 0; fm < 4; ++fm)
#pragma unroll
        for (int fn = 0; fn < 4; ++fn)
          acc[fm][fn] = __builtin_amdgcn_mfma_f32_16x16x32_bf16(
              af[fm][ks], bfr[fn][ks], acc[fm][fn], 0, 0, 0);
  }
  // ---- elu+1 and per-head z-scale ----
#pragma unroll
  for (int fm = 0; fm < 4; ++fm)
#pragma unroll
    for (int r = 0; r < 4; ++r) {
      float q[4];
#pragma unroll
      for (int fn = 0; fn < 4; ++fn) {
        float v = acc[fm][fn][r];
        q[fn] = v > 0.f ? v + 1.f : __expf(v);
      }
      float zd0 = q[0] * ksv[0] + q[1] * ksv[1];
      float zd1 = q[2] * ksv[2] + q[3] * ksv[3];
#pragma unroll
      for (int off = 1; off < 16; off <<= 1) {
        zd0 += __shfl_xor(zd0, off);
        zd1 += __shfl_xor(zd1, off);
      }
      float z0 = 4096.f / (zd0 + 1e-6f);
      float z1 = 4096.f / (zd1 + 1e-6f);
      acc[fm][0][r] = q[0] * z0; acc[fm][1][r] = q[1] * z0;
      acc[fm][2][r] = q[2] * z1; acc[fm][3][r] = q[3] * z1;
    }
  // ---- phase 2: msg = Qs @ Wcomb; B direct-from-global; two K-halves -------
  f32x4 acc2[4][4] = {};
  const u16* Bw = wc + (size_t)b * 65536;
  for (int hh = 0; hh < 2; ++hh) {
    __syncthreads();                 // prior Qlds / phase-1 LDS reads complete
    if ((wn >> 7) == hh) {
#pragma unroll
      for (int fm = 0; fm < 4; ++fm)
#pragma unroll
        for (int fn = 0; fn < 4; ++fn)
#pragma unroll
          for (int r = 0; r < 4; ++r)
            Qlds[(wm + fm * 16 + lk * 4 + r) * 136 + (wn & 64) + fn * 16 + lr] =
                f2bf(acc[fm][fn][r]);
    }
    __syncthreads();                 // Qlds visible
#pragma unroll
    for (int kc2 = 0; kc2 < 4; ++kc2) {
      bf16x8 a2[4], b2f[4];
#pragma unroll
      for (int fn = 0; fn < 4; ++fn)
        b2f[fn] = *(const bf16x8*)(Bw + (size_t)(wn + fn * 16 + lr) * 256 +
                                   hh * 128 + kc2 * 32 + lk * 8);
#pragma unroll
      for (int f = 0; f < 4; ++f)
        a2[f] = *(const bf16x8*)&Qlds[(wm + f * 16 + lr) * 136 + kc2 * 32 + lk * 8];
#pragma unroll
      for (int fm = 0; fm < 4; ++fm)
#pragma unroll
        for (int fn = 0; fn < 4; ++fn)
          acc2[fm][fn] = __builtin_amdgcn_mfma_f32_16x16x32_bf16(
              a2[fm], b2f[fn], acc2[fm][fn], 0, 0, 0);
    }
  }
  // ---- LN1 cross-wave ----
#pragma unroll
  for (int fm = 0; fm < 4; ++fm)
#pragma unroll
    for (int r = 0; r < 4; ++r) {
      float s = 0.f, sq = 0.f;
#pragma unroll
      for (int fn = 0; fn < 4; ++fn) {
        float a = acc2[fm][fn][r];
        s += a; sq += a * a;
      }
#pragma unroll
      for (int off = 1; off < 16; off <<= 1) {
        s += __shfl_xor(s, off);
        sq += __shfl_xor(sq, off);
      }
      if (lr == 0) {
        int row = wm + fm * 16 + lk * 4 + r;
        scr[row * 8 + (w & 3) * 2] = s;
        scr[row * 8 + (w & 3) * 2 + 1] = sq;
      }
    }
  __syncthreads();
  float gvs[4], bvs[4];
#pragma unroll
  for (int fn = 0; fn < 4; ++fn) {
    gvs[fn] = g1[wn + fn * 16 + lr];
    bvs[fn] = b1[wn + fn * 16 + lr];
  }
#pragma unroll
  for (int fm = 0; fm < 4; ++fm)
#pragma unroll
    for (int r = 0; r < 4; ++r) {
      int row = wm + fm * 16 + lk * 4 + r;
      float s = 0.f, sq = 0.f;
#pragma unroll
      for (int j = 0; j < 4; ++j) {
        s += scr[row * 8 + j * 2];
        sq += scr[row * 8 + j * 2 + 1];
      }
      float mu = s * (1.f / 256.f);
      float var = sq * (1.f / 256.f) - mu * mu;
      float rstd = rsqrtf(var + 1e-5f);
#pragma unroll
      for (int fn = 0; fn < 4; ++fn) {
        float y = (acc2[fm][fn][r] - mu) * rstd * gvs[fn] + bvs[fn];
        catout[(size_t)(m0 + row) * 512 + 256 + wn + fn * 16 + lr] = f2bf(y);
      }
    }
}

// ---- FUSED: MLP2 + LN2 + bf16-residual + transpose -> out -------------------
__global__ __launch_bounds__(512) void mlp2_tail_kernel(
    const u16* __restrict__ hidden, const u16* __restrict__ W2T,
    const float* __restrict__ g2, const float* __restrict__ b2,
    const u16* __restrict__ catp, float* __restrict__ out) {
  __shared__ alignas(16) char smem[16384 + 32768 + 4096 + 2048];
  u16* sA = (u16*)smem;                   // [128][64]
  u16* sB = (u16*)(smem + 16384);         // [256][64]
  float* scr = (float*)(smem + 49152);    // [128][8]
  float* sG = (float*)(smem + 53248);     // g2|b2
  float* T = (float*)smem;                // [64][129] overlay, post-GEMM
  const int t = threadIdx.x;
  const int m0 = blockIdx.x * 128;
  const int b = m0 >> 12, l0 = m0 & 4095;
  if (t < 256) { sG[t] = g2[t]; sG[256 + t] = b2[t]; }
  const int w = t >> 6, lane = t & 63;
  const int wm = (w >> 2) * 64, wn = (w & 3) * 64;
  const int lr = lane & 15, lk = lane >> 4;
  f32x4 acc[4][4] = {};
  for (int kt = 0; kt < 8; ++kt) {
    __syncthreads();
#pragma unroll
    for (int i = 0; i < 2; ++i) {
      int id = t + i * 512, row = id >> 3, chn = (id & 7) << 3;
      GLDS16(hidden + (size_t)(m0 + row) * 512 + kt * 64 + chn, sA + id * 8);
    }
#pragma unroll
    for (int i = 0; i < 4; ++i) {
      int id = t + i * 512, row = id >> 3, chn = (id & 7) << 3;
      GLDS16(W2T + (size_t)row * 512 + kt * 64 + chn, sB + id * 8);
    }
    __syncthreads();
    bf16x8 af[4][2], bfr[4][2];
#pragma unroll
    for (int f = 0; f < 4; ++f) {
#pragma unroll
      for (int ks = 0; ks < 2; ++ks) {
        af[f][ks] = *reinterpret_cast<const bf16x8*>(
            &sA[(wm + f * 16 + lr) * 64 + ks * 32 + lk * 8]);
        bfr[f][ks] = *reinterpret_cast<const bf16x8*>(
            &sB[(wn + f * 16 + lr) * 64 + ks * 32 + lk * 8]);
      }
    }
#pragma unroll
    for (int ks = 0; ks < 2; ++ks)
#pragma unroll
      for (int fm = 0; fm < 4; ++fm)
#pragma unroll
        for (int fn = 0; fn < 4; ++fn)
          acc[fm][fn] = __builtin_amdgcn_mfma_f32_16x16x32_bf16(
              af[fm][ks], bfr[fn][ks], acc[fm][fn], 0, 0, 0);
  }
  // ---- LN2 cross-wave ----
#pragma unroll
  for (int fm = 0; fm < 4; ++fm)
#pragma unroll
    for (int r = 0; r < 4; ++r) {
      float s = 0.f, sq = 0.f;
#pragma unroll
      for (int fn = 0; fn < 4; ++fn) {
        float a = acc[fm][fn][r];
        s += a; sq += a * a;
      }
#pragma unroll
      for (int off = 1; off < 16; off <<= 1) {
        s += __shfl_xor(s, off);
        sq += __shfl_xor(sq, off);
      }
      if (lr == 0) {
        int row = wm + fm * 16 + lk * 4 + r;
        scr[row * 8 + (w & 3) * 2] = s;
        scr[row * 8 + (w & 3) * 2 + 1] = sq;
      }
    }
  __syncthreads();
  float gvs[4], bvs[4];
#pragma unroll
  for (int fn = 0; fn < 4; ++fn) {
    gvs[fn] = sG[wn + fn * 16 + lr];
    bvs[fn] = sG[256 + wn + fn * 16 + lr];
  }
#pragma unroll
  for (int fm = 0; fm < 4; ++fm)
#pragma unroll
    for (int r = 0; r < 4; ++r) {
      int row = wm + fm * 16 + lk * 4 + r;
      float s = 0.f, sq = 0.f;
#pragma unroll
      for (int j = 0; j < 4; ++j) {
        s += scr[row * 8 + j * 2];
        sq += scr[row * 8 + j * 2 + 1];
      }
      float mu = s * (1.f / 256.f);
      float var = sq * (1.f / 256.f) - mu * mu;
      float rstd = rsqrtf(var + 1e-5f);
#pragma unroll
      for (int fn = 0; fn < 4; ++fn) {
        float xs = bf2f(catp[(size_t)(m0 + row) * 512 + wn + fn * 16 + lr]);
        acc[fm][fn][r] = (acc[fm][fn][r] - mu) * rstd * gvs[fn] + bvs[fn] + xs;
      }
    }
  __syncthreads();
  // ---- transpose chunks of 64 cols, coalesced f32 write ----
  for (int cc = 0; cc < 4; ++cc) {
    if ((w & 3) == cc) {
#pragma unroll
      for (int fm = 0; fm < 4; ++fm)
#pragma unroll
        for (int fn = 0; fn < 4; ++fn)
#pragma unroll
          for (int r = 0; r < 4; ++r)
            T[(fn * 16 + lr) * 129 + wm + fm * 16 + lk * 4 + r] = acc[fm][fn][r];
    }
    __syncthreads();
#pragma unroll
    for (int i = 0; i < 4; ++i) {
      int idx = t + i * 512;
      int cT = idx >> 5, lq = (idx & 31) * 4;
      int cg = cc * 64 + cT;
      size_t o = ((size_t)b * 256 + cg) * 4096 + l0 + lq;
      float4 ov;
      ov.x = T[cT * 129 + lq];
      ov.y = T[cT * 129 + lq + 1];
      ov.z = T[cT * 129 + lq + 2];
      ov.w = T[cT * 129 + lq + 3];
      *reinterpret_cast<float4*>(out + o) = ov;
    }
    __syncthreads();
  }
}

extern "C" void kernel_launch(void* const* d_in, const int* in_sizes, int n_in,
                              void* d_out, int out_size, void* d_ws, size_t ws_size,
                              hipStream_t stream) {
  (void)in_sizes; (void)n_in; (void)out_size; (void)ws_size;
  const float* x = (const float*)d_in[0];
  const float* srcp = (const float*)d_in[1];
  const float* Wq = (const float*)d_in[2];
  const float* Wk = (const float*)d_in[3];
  const float* Wv = (const float*)d_in[4];
  const float* Wm = (const float*)d_in[5];
  const float* W1 = (const float*)d_in[6];
  const float* W2 = (const float*)d_in[7];
  const float* g1 = (const float*)d_in[8];
  const float* b1 = (const float*)d_in[9];
  const float* g2 = (const float*)d_in[10];
  const float* b2 = (const float*)d_in[11];
  float* out = (float*)d_out;
  char* ws = (char*)d_ws;

  u16* wqt = (u16*)(ws + OFF_WQ);
  u16* wkvt = (u16*)(ws + OFF_WK);
  u16* wkt = (u16*)(ws + OFF_WK);
  u16* wvt = (u16*)(ws + OFF_WV);
  u16* wmt = (u16*)(ws + OFF_WM);
  u16* w1t = (u16*)(ws + OFF_W1);
  u16* w2t = (u16*)(ws + OFF_W2);
  u16* cat = (u16*)(ws + OFF_CAT);
  u16* ssb = (u16*)(ws + OFF_SSB);
  u16* kvproj = (u16*)(ws + OFF_KVPROJ);
  float* KSb = (float*)(ws + OFF_KS);
  float* KVp = (float*)(ws + OFF_KVP);
  float* KSp = (float*)(ws + OFF_KSP);
  u16* wcombT = (u16*)(ws + OFF_WC);
  u16* hidden = kvproj;

  dim3 blk(256);
  wprep_all_kernel<<<dim3(640), blk, 0, stream>>>(Wq, Wk, Wv, Wm, W1, W2,
                                                  wqt, wkt, wvt, wmt, w1t, w2t);
  transpose_in_kernel<<<dim3(64, 4, 16), blk, 0, stream>>>(x, srcp, cat, ssb);
  gemm256_kernel<4><<<dim3(512), dim3(512), 0, stream>>>(ssb, 256, wkvt, 256, kvproj, 512);
  kv_partial_kernel<<<dim3(512), blk, 0, stream>>>(kvproj, KVp, KSp);
  kvred_wcomb_kernel<<<dim3(64), blk, 0, stream>>>(KVp, KSp, wmt, wcombT, KSb);
  qmsg_kernel<<<dim3(256), dim3(512), 0, stream>>>(cat, wqt, KSb, wcombT, g1, b1, cat);
  gemm256_kernel<3><<<dim3(512), dim3(512), 0, stream>>>(cat, 512, w1t, 512, hidden, 512);
  mlp2_tail_kernel<<<dim3(256), dim3(512), 0, stream>>>(hidden, w2t, g2, b2, cat, out);
}

// Round 11
// 154.494 us; speedup vs baseline: 1.0418x; 1.0418x over previous
//
#include <hip/hip_runtime.h>

typedef unsigned short u16;
typedef __bf16 bf16x8 __attribute__((ext_vector_type(8)));
typedef float f32x4 __attribute__((ext_vector_type(4)));

__device__ __forceinline__ u16 f2bf(float f) {
  unsigned int u = __float_as_uint(f);
  u += 0x7fffu + ((u >> 16) & 1u);
  return (u16)(u >> 16);
}
__device__ __forceinline__ float bf2f(u16 v) {
  return __uint_as_float(((unsigned)v) << 16);
}

#define GLDS16(gp, lp)                                                   \
  __builtin_amdgcn_global_load_lds(                                      \
      (const __attribute__((address_space(1))) unsigned int*)(gp),       \
      (__attribute__((address_space(3))) unsigned int*)(lp), 16, 0, 0)

// B=8, C=256, L=4096, M=32768, NHEAD=8, dim=32
// ws layout (bytes)
#define OFF_WQ     0u
#define OFF_WK     131072u     /* wkvt rows 0:256 */
#define OFF_WV     262144u
#define OFF_WM     393216u
#define OFF_W1     524288u
#define OFF_W2     1048576u
#define OFF_CAT    1310720u    /* u16 [M][512]: 0:256 xs, 256:512 ln1 */
#define OFF_SSB    34865152u   /* u16 [M][256] ss_bf16 */
#define OFF_KVPROJ 68419584u   /* u16 [M][512] K|vals bf16 ; later hidden */
#define OFF_KS     152567808u  /* f32 [64][32] Ksum */
#define OFF_KVP    152576000u  /* f32 [8][64][32][32] partials */
#define OFF_KSP    154673152u  /* f32 [8][64][32] partials */
#define OFF_WC     154740736u  /* u16 [8][256][256] wcomb */

// ---- merged prep: input transposes (blocks 0..4095) + weight prep (..4735) --
// transpose: fp32 [C,L] -> bf16 [L,C], 64x64 tiles, uint4 writes
// wprep: fp32 [K,N] -> bf16 [N,K]
__global__ __launch_bounds__(256) void prep_kernel(
    const float* __restrict__ x, const float* __restrict__ srcp,
    u16* __restrict__ cat, u16* __restrict__ ssb,
    const float* __restrict__ Wq, const float* __restrict__ Wk,
    const float* __restrict__ Wv, const float* __restrict__ Wm,
    const float* __restrict__ W1, const float* __restrict__ W2,
    u16* __restrict__ dq, u16* __restrict__ dk, u16* __restrict__ dv,
    u16* __restrict__ dm, u16* __restrict__ d1, u16* __restrict__ d2) {
  __shared__ float s[64 * 65];
  const int bid = blockIdx.x;
  const int t = threadIdx.x;
  if (bid < 4096) {
    const int bx = bid & 63, by = (bid >> 6) & 3, z = bid >> 8;
    const float* src = z < 8 ? x : srcp;
    u16* dst = z < 8 ? cat : ssb;
    const int dstride = z < 8 ? 512 : 256;
    const int b = z & 7;
    const int lt = bx * 64, ct = by * 64;
    const int cl = t >> 2, loff = (t & 3) * 16;
#pragma unroll
    for (int j = 0; j < 4; ++j) {
      float4 v = *reinterpret_cast<const float4*>(
          src + ((size_t)b * 256 + ct + cl) * 4096 + lt + loff + j * 4);
      s[cl * 65 + loff + j * 4 + 0] = v.x;
      s[cl * 65 + loff + j * 4 + 1] = v.y;
      s[cl * 65 + loff + j * 4 + 2] = v.z;
      s[cl * 65 + loff + j * 4 + 3] = v.w;
    }
    __syncthreads();
#pragma unroll
    for (int i = 0; i < 2; ++i) {
      int id = t + i * 256;          // 0..511
      int ll = id >> 3, cg = id & 7;
      unsigned pk[4];
#pragma unroll
      for (int j = 0; j < 4; ++j) {
        unsigned lo = f2bf(s[(cg * 8 + j * 2) * 65 + ll]);
        unsigned hi = f2bf(s[(cg * 8 + j * 2 + 1) * 65 + ll]);
        pk[j] = lo | (hi << 16);
      }
      uint4 val = {pk[0], pk[1], pk[2], pk[3]};
      *reinterpret_cast<uint4*>(
          dst + ((size_t)b * 4096 + lt + ll) * dstride + ct + cg * 8) = val;
    }
  } else {
    const int wb = bid - 4096;
    const float* src; u16* dst; int Kd, Nd, tt;
    if (wb < 64)       { src = Wq; dst = dq; Kd = 256; Nd = 256; tt = wb; }
    else if (wb < 128) { src = Wk; dst = dk; Kd = 256; Nd = 256; tt = wb - 64; }
    else if (wb < 192) { src = Wv; dst = dv; Kd = 256; Nd = 256; tt = wb - 128; }
    else if (wb < 256) { src = Wm; dst = dm; Kd = 256; Nd = 256; tt = wb - 192; }
    else if (wb < 512) { src = W1; dst = d1; Kd = 512; Nd = 512; tt = wb - 256; }
    else               { src = W2; dst = d2; Kd = 512; Nd = 256; tt = wb - 512; }
    int ntn = Nd >> 5;
    int kt = (tt / ntn) * 32, nt = (tt % ntn) * 32;
    int tx = t & 31, ty = t >> 5;
#pragma unroll
    for (int i = 0; i < 4; ++i)
      s[(ty + i * 8) * 33 + tx] = src[(size_t)(kt + ty + i * 8) * Nd + nt + tx];
    __syncthreads();
#pragma unroll
    for (int i = 0; i < 4; ++i)
      dst[(size_t)(nt + ty + i * 8) * Kd + kt + tx] = f2bf(s[tx * 33 + ty + i * 8]);
  }
}

// ---- bf16 MFMA GEMM, 128x256 tile, 8 waves (2m x 4n), gload_lds staging -----
// Grid 512 linear, XCD-chunked. EPI: 3 relu bf16 | 4 fused kv bf16
template <int EPI>
__global__ __launch_bounds__(512) void gemm256_kernel(
    const u16* __restrict__ A, int lda, const u16* __restrict__ Wt, int K,
    u16* __restrict__ outp, int ldo) {
  __shared__ alignas(16) u16 sA[128 * 64];
  __shared__ alignas(16) u16 sB[256 * 64];
  const int t = threadIdx.x;
  int bid = blockIdx.x;
  int xcd = bid & 7, i0 = bid >> 3;
  const int m0 = (xcd * 32 + (i0 >> 1)) * 128;
  const int n0 = (i0 & 1) * 256;
  const int w = t >> 6, lane = t & 63;
  const int wm = (w >> 2) * 64, wn = (w & 3) * 64;
  const int lr = lane & 15, lk = lane >> 4;
  f32x4 acc[4][4] = {};
  const int nkt = K >> 6;
  for (int kt = 0; kt < nkt; ++kt) {
    __syncthreads();
#pragma unroll
    for (int i = 0; i < 2; ++i) {
      int id = t + i * 512, row = id >> 3, ch = (id & 7) << 3;
      GLDS16(A + (size_t)(m0 + row) * lda + kt * 64 + ch, sA + id * 8);
    }
#pragma unroll
    for (int i = 0; i < 4; ++i) {
      int id = t + i * 512, row = id >> 3, ch = (id & 7) << 3;
      GLDS16(Wt + (size_t)(n0 + row) * K + kt * 64 + ch, sB + id * 8);
    }
    __syncthreads();
    bf16x8 af[4][2], bfr[4][2];
#pragma unroll
    for (int f = 0; f < 4; ++f) {
#pragma unroll
      for (int ks = 0; ks < 2; ++ks) {
        af[f][ks] = *reinterpret_cast<const bf16x8*>(
            &sA[(wm + f * 16 + lr) * 64 + ks * 32 + lk * 8]);
        bfr[f][ks] = *reinterpret_cast<const bf16x8*>(
            &sB[(wn + f * 16 + lr) * 64 + ks * 32 + lk * 8]);
      }
    }
#pragma unroll
    for (int ks = 0; ks < 2; ++ks)
#pragma unroll
      for (int fm = 0; fm < 4; ++fm)
#pragma unroll
        for (int fn = 0; fn < 4; ++fn)
          acc[fm][fn] = __builtin_amdgcn_mfma_f32_16x16x32_bf16(
              af[fm][ks], bfr[fn][ks], acc[fm][fn], 0, 0, 0);
  }
  const int r0 = (lane >> 4) * 4, c0 = lane & 15;
#pragma unroll
  for (int fm = 0; fm < 4; ++fm) {
#pragma unroll
    for (int fn = 0; fn < 4; ++fn) {
      int gr = m0 + wm + fm * 16 + r0;
      int gc = n0 + wn + fn * 16 + c0;
#pragma unroll
      for (int r = 0; r < 4; ++r) {
        float v = acc[fm][fn][r];
        if (EPI == 3) v = v > 0.f ? v : 0.f;
        if (EPI == 4) v = (gc < 256) ? (v > 0.f ? v + 1.f : __expf(v)) : v * (1.f / 4096.f);
        outp[(size_t)(gr + r) * ldo + gc] = f2bf(v);
      }
    }
  }
}

// ---- KV partial over L-slices (reads bf16 kvproj [M][512]) ------------------
__global__ __launch_bounds__(256) void kv_partial_kernel(
    const u16* __restrict__ KVproj, float* __restrict__ KVp,
    float* __restrict__ KSp) {
  __shared__ alignas(16) float sK[64][32];
  __shared__ alignas(16) float sV[64][32];
  const int bh = blockIdx.x, sl = blockIdx.y;
  const int b = bh >> 3, h = bh & 7;
  const int t = threadIdx.x;
  const int lrow = t >> 2, lcol = (t & 3) * 8;
  const int d = t >> 3, vg = (t & 7) * 4;
  float a0 = 0, a1 = 0, a2 = 0, a3 = 0, ks = 0;
  for (int lt = 0; lt < 512; lt += 64) {
    __syncthreads();
    size_t roff = ((size_t)b * 4096 + sl * 512 + lt + lrow) * 512 + h * 32 + lcol;
    uint4 kq = *reinterpret_cast<const uint4*>(KVproj + roff);
    uint4 vq = *reinterpret_cast<const uint4*>(KVproj + roff + 256);
    float* dk = &sK[lrow][lcol];
    float* dv = &sV[lrow][lcol];
#pragma unroll
    for (int j = 0; j < 4; ++j) {
      unsigned uk = ((const unsigned*)&kq)[j];
      unsigned uv = ((const unsigned*)&vq)[j];
      dk[2 * j] = __uint_as_float(uk << 16);
      dk[2 * j + 1] = __uint_as_float(uk & 0xffff0000u);
      dv[2 * j] = __uint_as_float(uv << 16);
      dv[2 * j + 1] = __uint_as_float(uv & 0xffff0000u);
    }
    __syncthreads();
#pragma unroll 8
    for (int i = 0; i < 64; ++i) {
      float kd = sK[i][d];
      a0 += kd * sV[i][vg + 0];
      a1 += kd * sV[i][vg + 1];
      a2 += kd * sV[i][vg + 2];
      a3 += kd * sV[i][vg + 3];
      ks += kd;
    }
  }
  float* o = KVp + (size_t)sl * 65536 + bh * 1024 + d * 32 + vg;
  o[0] = a0; o[1] = a1; o[2] = a2; o[3] = a3;
  if ((t & 7) == 0) KSp[(size_t)sl * 2048 + bh * 32 + d] = ks;
}

// ---- merged: reduce KVp -> KV[b] (LDS) ; Ksum ; wcomb chunk -----------------
__global__ __launch_bounds__(256) void kvred_wcomb_kernel(
    const float* __restrict__ KVp, const float* __restrict__ KSp,
    const u16* __restrict__ wmt, u16* __restrict__ wc,
    float* __restrict__ Ksum) {
  __shared__ float sKV[8 * 1032];
  const int b = blockIdx.x >> 3, nc = blockIdx.x & 7;
  const int t = threadIdx.x;
#pragma unroll
  for (int i = 0; i < 32; ++i) {
    int idx = t + i * 256;
    float s = 0.f;
#pragma unroll
    for (int sl = 0; sl < 8; ++sl) s += KVp[(size_t)sl * 65536 + b * 8192 + idx];
    sKV[(idx >> 10) * 1032 + (idx & 1023)] = s;
  }
  if (nc == 0) {
    float s = 0.f;
#pragma unroll
    for (int sl = 0; sl < 8; ++sl) s += KSp[(size_t)sl * 2048 + b * 256 + t];
    Ksum[b * 256 + t] = s;
  }
  __syncthreads();
  const int n = nc * 32 + (t >> 3), h = t & 7;
  float wmv[32];
  const u16* wmrow = wmt + (size_t)n * 256 + h * 32;
#pragma unroll
  for (int v = 0; v < 32; ++v) wmv[v] = bf2f(wmrow[v]);
  unsigned pk[16];
  const float* kvh = &sKV[h * 1032];
#pragma unroll
  for (int dp = 0; dp < 16; ++dp) {
    unsigned lohi[2];
#pragma unroll
    for (int e = 0; e < 2; ++e) {
      int d = dp * 2 + e;
      const float* kv = kvh + d * 32;
      float s = 0.f;
#pragma unroll
      for (int v = 0; v < 32; ++v) s += kv[v] * wmv[v];
      lohi[e] = f2bf(s);
    }
    pk[dp] = lohi[0] | (lohi[1] << 16);
  }
  uint4* dst = (uint4*)(wc + ((size_t)b * 256 + n) * 256 + h * 32);
#pragma unroll
  for (int j = 0; j < 4; ++j) {
    uint4 val = {pk[j * 4], pk[j * 4 + 1], pk[j * 4 + 2], pk[j * 4 + 3]};
    dst[j] = val;
  }
}

// ---- FUSED: Qproj + elu+1 + z-scale + (Qs @ Wcomb) + LN1 -> cat[:,256:512] --
// BM=128, 512 threads (8 waves 2m x 4n), grid 256. (R8-proven form)
__global__ __launch_bounds__(512) void qmsg_kernel(
    const u16* __restrict__ cat, const u16* __restrict__ WqT,
    const float* __restrict__ KSb, const u16* __restrict__ wc,
    const float* __restrict__ g1, const float* __restrict__ b1,
    u16* __restrict__ catout) {
  __shared__ alignas(16) char smem[57344];
  u16* sA = (u16*)smem;
  u16* sB = (u16*)(smem + 16384);
  u16* Qlds = (u16*)smem;
  u16* sWc = (u16*)(smem + 35840);
  float* scr = (float*)(smem + 52224);
  const int t = threadIdx.x;
  const int m0 = blockIdx.x * 128;
  const int b = m0 >> 12;
  const int w = t >> 6, lane = t & 63;
  const int wm = (w >> 2) * 64, wn = (w & 3) * 64;
  const int lr = lane & 15, lk = lane >> 4;
  f32x4 acc[4][4] = {};
  float ksv[4];
#pragma unroll
  for (int fn = 0; fn < 4; ++fn) ksv[fn] = KSb[b * 256 + wn + fn * 16 + lr];
  // ---- phase 1: Q-proj GEMM (K=256) ----
  for (int kt = 0; kt < 4; ++kt) {
    __syncthreads();
#pragma unroll
    for (int i = 0; i < 2; ++i) {
      int id = t + i * 512, row = id >> 3, ch = (id & 7) << 3;
      GLDS16(cat + (size_t)(m0 + row) * 512 + kt * 64 + ch, sA + id * 8);
    }
#pragma unroll
    for (int i = 0; i < 4; ++i) {
      int id = t + i * 512, row = id >> 3, ch = (id & 7) << 3;
      GLDS16(WqT + (size_t)row * 256 + kt * 64 + ch, sB + id * 8);
    }
    __syncthreads();
    bf16x8 af[4][2], bfr[4][2];
#pragma unroll
    for (int f = 0; f < 4; ++f)
#pragma unroll
      for (int ks = 0; ks < 2; ++ks) {
        af[f][ks] = *(const bf16x8*)&sA[(wm + f * 16 + lr) * 64 + ks * 32 + lk * 8];
        bfr[f][ks] = *(const bf16x8*)&sB[(wn + f * 16 + lr) * 64 + ks * 32 + lk * 8];
      }
#pragma unroll
    for (int ks = 0; ks < 2; ++ks)
#pragma unroll
      for (int fm = 0; fm < 4; ++fm)
#pragma unroll
        for (int fn = 0; fn < 4; ++fn)
          acc[fm][fn] = __builtin_amdgcn_mfma_f32_16x16x32_bf16(
              af[fm][ks], bfr[fn][ks], acc[fm][fn], 0, 0, 0);
  }
  // ---- elu+1 and per-head z-scale ----
#pragma unroll
  for (int fm = 0; fm < 4; ++fm)
#pragma unroll
    for (int r = 0; r < 4; ++r) {
      float q[4];
#pragma unroll
      for (int fn = 0; fn < 4; ++fn) {
        float v = acc[fm][fn][r];
        q[fn] = v > 0.f ? v + 1.f : __expf(v);
      }
      float zd0 = q[0] * ksv[0] + q[1] * ksv[1];
      float zd1 = q[2] * ksv[2] + q[3] * ksv[3];
#pragma unroll
      for (int off = 1; off < 16; off <<= 1) {
        zd0 += __shfl_xor(zd0, off);
        zd1 += __shfl_xor(zd1, off);
      }
      float z0 = 4096.f / (zd0 + 1e-6f);
      float z1 = 4096.f / (zd1 + 1e-6f);
      acc[fm][0][r] = q[0] * z0; acc[fm][1][r] = q[1] * z0;
      acc[fm][2][r] = q[2] * z1; acc[fm][3][r] = q[3] * z1;
    }
  // ---- phase 2: msg = Qs @ Wcomb, two 128-col K-halves through Qlds --------
  f32x4 acc2[4][4] = {};
  const u16* Bw = wc + (size_t)b * 65536;
  for (int hh = 0; hh < 2; ++hh) {
    __syncthreads();                 // prior Qlds/sA/sB reads complete
    if ((wn >> 7) == hh) {
#pragma unroll
      for (int fm = 0; fm < 4; ++fm)
#pragma unroll
        for (int fn = 0; fn < 4; ++fn)
#pragma unroll
          for (int r = 0; r < 4; ++r)
            Qlds[(wm + fm * 16 + lk * 4 + r) * 136 + (wn & 64) + fn * 16 + lr] =
                f2bf(acc[fm][fn][r]);
    }
    __syncthreads();                 // Qlds visible
    for (int kc2 = 0; kc2 < 4; ++kc2) {
#pragma unroll
      for (int i = 0; i < 2; ++i) {
        int id = t + i * 512, row = id >> 2, ch = (id & 3) << 3;
        GLDS16(Bw + (size_t)row * 256 + hh * 128 + kc2 * 32 +
                   (ch ^ ((row & 3) << 3)), sWc + id * 8);
      }
      __syncthreads();               // sWc staged
      bf16x8 a2[4], b2f[4];
#pragma unroll
      for (int f = 0; f < 4; ++f)
        a2[f] = *(const bf16x8*)&Qlds[(wm + f * 16 + lr) * 136 + kc2 * 32 + lk * 8];
#pragma unroll
      for (int fn = 0; fn < 4; ++fn) {
        int br = wn + fn * 16 + lr;
        b2f[fn] = *(const bf16x8*)&sWc[br * 32 + ((lk * 8) ^ ((br & 3) << 3))];
      }
#pragma unroll
      for (int fm = 0; fm < 4; ++fm)
#pragma unroll
        for (int fn = 0; fn < 4; ++fn)
          acc2[fm][fn] = __builtin_amdgcn_mfma_f32_16x16x32_bf16(
              a2[fm], b2f[fn], acc2[fm][fn], 0, 0, 0);
      __syncthreads();               // frag reads done before sWc/Qlds overwrite
    }
  }
  // ---- LN1 cross-wave ----
#pragma unroll
  for (int fm = 0; fm < 4; ++fm)
#pragma unroll
    for (int r = 0; r < 4; ++r) {
      float s = 0.f, sq = 0.f;
#pragma unroll
      for (int fn = 0; fn < 4; ++fn) {
        float a = acc2[fm][fn][r];
        s += a; sq += a * a;
      }
#pragma unroll
      for (int off = 1; off < 16; off <<= 1) {
        s += __shfl_xor(s, off);
        sq += __shfl_xor(sq, off);
      }
      if (lr == 0) {
        int row = wm + fm * 16 + lk * 4 + r;
        scr[row * 8 + (w & 3) * 2] = s;
        scr[row * 8 + (w & 3) * 2 + 1] = sq;
      }
    }
  __syncthreads();
  float gvs[4], bvs[4];
#pragma unroll
  for (int fn = 0; fn < 4; ++fn) {
    gvs[fn] = g1[wn + fn * 16 + lr];
    bvs[fn] = b1[wn + fn * 16 + lr];
  }
#pragma unroll
  for (int fm = 0; fm < 4; ++fm)
#pragma unroll
    for (int r = 0; r < 4; ++r) {
      int row = wm + fm * 16 + lk * 4 + r;
      float s = 0.f, sq = 0.f;
#pragma unroll
      for (int j = 0; j < 4; ++j) {
        s += scr[row * 8 + j * 2];
        sq += scr[row * 8 + j * 2 + 1];
      }
      float mu = s * (1.f / 256.f);
      float var = sq * (1.f / 256.f) - mu * mu;
      float rstd = rsqrtf(var + 1e-5f);
#pragma unroll
      for (int fn = 0; fn < 4; ++fn) {
        float y = (acc2[fm][fn][r] - mu) * rstd * gvs[fn] + bvs[fn];
        catout[(size_t)(m0 + row) * 512 + 256 + wn + fn * 16 + lr] = f2bf(y);
      }
    }
}

// ---- FUSED: MLP2 + LN2 + bf16-residual + transpose -> out -------------------
__global__ __launch_bounds__(512) void mlp2_tail_kernel(
    const u16* __restrict__ hidden, const u16* __restrict__ W2T,
    const float* __restrict__ g2, const float* __restrict__ b2,
    const u16* __restrict__ catp, float* __restrict__ out) {
  __shared__ alignas(16) char smem[16384 + 32768 + 4096 + 2048];
  u16* sA = (u16*)smem;                   // [128][64]
  u16* sB = (u16*)(smem + 16384);         // [256][64]
  float* scr = (float*)(smem + 49152);    // [128][8]
  float* sG = (float*)(smem + 53248);     // g2|b2
  float* T = (float*)smem;                // [64][129] overlay, post-GEMM
  const int t = threadIdx.x;
  const int m0 = blockIdx.x * 128;
  const int b = m0 >> 12, l0 = m0 & 4095;
  if (t < 256) { sG[t] = g2[t]; sG[256 + t] = b2[t]; }
  const int w = t >> 6, lane = t & 63;
  const int wm = (w >> 2) * 64, wn = (w & 3) * 64;
  const int lr = lane & 15, lk = lane >> 4;
  f32x4 acc[4][4] = {};
  for (int kt = 0; kt < 8; ++kt) {
    __syncthreads();
#pragma unroll
    for (int i = 0; i < 2; ++i) {
      int id = t + i * 512, row = id >> 3, chn = (id & 7) << 3;
      GLDS16(hidden + (size_t)(m0 + row) * 512 + kt * 64 + chn, sA + id * 8);
    }
#pragma unroll
    for (int i = 0; i < 4; ++i) {
      int id = t + i * 512, row = id >> 3, chn = (id & 7) << 3;
      GLDS16(W2T + (size_t)row * 512 + kt * 64 + chn, sB + id * 8);
    }
    __syncthreads();
    bf16x8 af[4][2], bfr[4][2];
#pragma unroll
    for (int f = 0; f < 4; ++f) {
#pragma unroll
      for (int ks = 0; ks < 2; ++ks) {
        af[f][ks] = *reinterpret_cast<const bf16x8*>(
            &sA[(wm + f * 16 + lr) * 64 + ks * 32 + lk * 8]);
        bfr[f][ks] = *reinterpret_cast<const bf16x8*>(
            &sB[(wn + f * 16 + lr) * 64 + ks * 32 + lk * 8]);
      }
    }
#pragma unroll
    for (int ks = 0; ks < 2; ++ks)
#pragma unroll
      for (int fm = 0; fm < 4; ++fm)
#pragma unroll
        for (int fn = 0; fn < 4; ++fn)
          acc[fm][fn] = __builtin_amdgcn_mfma_f32_16x16x32_bf16(
              af[fm][ks], bfr[fn][ks], acc[fm][fn], 0, 0, 0);
  }
  // ---- LN2 cross-wave ----
#pragma unroll
  for (int fm = 0; fm < 4; ++fm)
#pragma unroll
    for (int r = 0; r < 4; ++r) {
      float s = 0.f, sq = 0.f;
#pragma unroll
      for (int fn = 0; fn < 4; ++fn) {
        float a = acc[fm][fn][r];
        s += a; sq += a * a;
      }
#pragma unroll
      for (int off = 1; off < 16; off <<= 1) {
        s += __shfl_xor(s, off);
        sq += __shfl_xor(sq, off);
      }
      if (lr == 0) {
        int row = wm + fm * 16 + lk * 4 + r;
        scr[row * 8 + (w & 3) * 2] = s;
        scr[row * 8 + (w & 3) * 2 + 1] = sq;
      }
    }
  __syncthreads();
  float gvs[4], bvs[4];
#pragma unroll
  for (int fn = 0; fn < 4; ++fn) {
    gvs[fn] = sG[wn + fn * 16 + lr];
    bvs[fn] = sG[256 + wn + fn * 16 + lr];
  }
#pragma unroll
  for (int fm = 0; fm < 4; ++fm)
#pragma unroll
    for (int r = 0; r < 4; ++r) {
      int row = wm + fm * 16 + lk * 4 + r;
      float s = 0.f, sq = 0.f;
#pragma unroll
      for (int j = 0; j < 4; ++j) {
        s += scr[row * 8 + j * 2];
        sq += scr[row * 8 + j * 2 + 1];
      }
      float mu = s * (1.f / 256.f);
      float var = sq * (1.f / 256.f) - mu * mu;
      float rstd = rsqrtf(var + 1e-5f);
#pragma unroll
      for (int fn = 0; fn < 4; ++fn) {
        float xs = bf2f(catp[(size_t)(m0 + row) * 512 + wn + fn * 16 + lr]);
        acc[fm][fn][r] = (acc[fm][fn][r] - mu) * rstd * gvs[fn] + bvs[fn] + xs;
      }
    }
  __syncthreads();
  // ---- transpose chunks of 64 cols, coalesced f32 write ----
  for (int cc = 0; cc < 4; ++cc) {
    if ((w & 3) == cc) {
#pragma unroll
      for (int fm = 0; fm < 4; ++fm)
#pragma unroll
        for (int fn = 0; fn < 4; ++fn)
#pragma unroll
          for (int r = 0; r < 4; ++r)
            T[(fn * 16 + lr) * 129 + wm + fm * 16 + lk * 4 + r] = acc[fm][fn][r];
    }
    __syncthreads();
#pragma unroll
    for (int i = 0; i < 4; ++i) {
      int idx = t + i * 512;
      int cT = idx >> 5, lq = (idx & 31) * 4;
      int cg = cc * 64 + cT;
      size_t o = ((size_t)b * 256 + cg) * 4096 + l0 + lq;
      float4 ov;
      ov.x = T[cT * 129 + lq];
      ov.y = T[cT * 129 + lq + 1];
      ov.z = T[cT * 129 + lq + 2];
      ov.w = T[cT * 129 + lq + 3];
      *reinterpret_cast<float4*>(out + o) = ov;
    }
    __syncthreads();
  }
}

extern "C" void kernel_launch(void* const* d_in, const int* in_sizes, int n_in,
                              void* d_out, int out_size, void* d_ws, size_t ws_size,
                              hipStream_t stream) {
  (void)in_sizes; (void)n_in; (void)out_size; (void)ws_size;
  const float* x = (const float*)d_in[0];
  const float* srcp = (const float*)d_in[1];
  const float* Wq = (const float*)d_in[2];
  const float* Wk = (const float*)d_in[3];
  const float* Wv = (const float*)d_in[4];
  const float* Wm = (const float*)d_in[5];
  const float* W1 = (const float*)d_in[6];
  const float* W2 = (const float*)d_in[7];
  const float* g1 = (const float*)d_in[8];
  const float* b1 = (const float*)d_in[9];
  const float* g2 = (const float*)d_in[10];
  const float* b2 = (const float*)d_in[11];
  float* out = (float*)d_out;
  char* ws = (char*)d_ws;

  u16* wqt = (u16*)(ws + OFF_WQ);
  u16* wkvt = (u16*)(ws + OFF_WK);
  u16* wkt = (u16*)(ws + OFF_WK);
  u16* wvt = (u16*)(ws + OFF_WV);
  u16* wmt = (u16*)(ws + OFF_WM);
  u16* w1t = (u16*)(ws + OFF_W1);
  u16* w2t = (u16*)(ws + OFF_W2);
  u16* cat = (u16*)(ws + OFF_CAT);
  u16* ssb = (u16*)(ws + OFF_SSB);
  u16* kvproj = (u16*)(ws + OFF_KVPROJ);
  float* KSb = (float*)(ws + OFF_KS);
  float* KVp = (float*)(ws + OFF_KVP);
  float* KSp = (float*)(ws + OFF_KSP);
  u16* wcombT = (u16*)(ws + OFF_WC);
  u16* hidden = kvproj;

  dim3 blk(256);
  prep_kernel<<<dim3(4736), blk, 0, stream>>>(x, srcp, cat, ssb,
                                              Wq, Wk, Wv, Wm, W1, W2,
                                              wqt, wkt, wvt, wmt, w1t, w2t);
  gemm256_kernel<4><<<dim3(512), dim3(512), 0, stream>>>(ssb, 256, wkvt, 256, kvproj, 512);
  kv_partial_kernel<<<dim3(64, 8), blk, 0, stream>>>(kvproj, KVp, KSp);
  kvred_wcomb_kernel<<<dim3(64), blk, 0, stream>>>(KVp, KSp, wmt, wcombT, KSb);
  qmsg_kernel<<<dim3(256), dim3(512), 0, stream>>>(cat, wqt, KSb, wcombT, g1, b1, cat);
  gemm256_kernel<3><<<dim3(512), dim3(512), 0, stream>>>(cat, 512, w1t, 512, hidden, 512);
  mlp2_tail_kernel<<<dim3(256), dim3(512), 0, stream>>>(hidden, w2t, g2, b2, cat, out);
}

// Round 14
// 153.671 us; speedup vs baseline: 1.0474x; 1.0054x over previous
//
#include <hip/hip_runtime.h>

typedef unsigned short u16;
typedef __bf16 bf16x8 __attribute__((ext_vector_type(8)));
typedef float f32x4 __attribute__((ext_vector_type(4)));

__device__ __forceinline__ u16 f2bf(float f) {
  unsigned int u = __float_as_uint(f);
  u += 0x7fffu + ((u >> 16) & 1u);
  return (u16)(u >> 16);
}
__device__ __forceinline__ float bf2f(u16 v) {
  return __uint_as_float(((unsigned)v) << 16);
}

#define GLDS16(gp, lp)                                                   \
  __builtin_amdgcn_global_load_lds(                                      \
      (const __attribute__((address_space(1))) unsigned int*)(gp),       \
      (__attribute__((address_space(3))) unsigned int*)(lp), 16, 0, 0)

// B=8, C=256, L=4096, M=32768, NHEAD=8, dim=32
// ws layout (bytes)
#define OFF_WQ     0u
#define OFF_WK     131072u     /* wkvt rows 0:256 */
#define OFF_WV     262144u
#define OFF_WM     393216u
#define OFF_W1     524288u
#define OFF_W2     1048576u
#define OFF_CAT    1310720u    /* u16 [M][512]: 0:256 xs, 256:512 ln1 */
#define OFF_SSB    34865152u   /* u16 [M][256] ss_bf16 */
#define OFF_KVPROJ 68419584u   /* u16 [M][512] K|vals bf16 ; later hidden */
#define OFF_KS     152567808u  /* f32 [64][32] Ksum */
#define OFF_KVP    152576000u  /* f32 [8][64][32][32] partials */
#define OFF_KSP    154673152u  /* f32 [8][64][32] partials */
#define OFF_WC     154740736u  /* u16 [8][256][256] wcomb */

// ---- merged prep: input transposes (blocks 0..4095) + weight prep (..4735) --
__global__ __launch_bounds__(256) void prep_kernel(
    const float* __restrict__ x, const float* __restrict__ srcp,
    u16* __restrict__ cat, u16* __restrict__ ssb,
    const float* __restrict__ Wq, const float* __restrict__ Wk,
    const float* __restrict__ Wv, const float* __restrict__ Wm,
    const float* __restrict__ W1, const float* __restrict__ W2,
    u16* __restrict__ dq, u16* __restrict__ dk, u16* __restrict__ dv,
    u16* __restrict__ dm, u16* __restrict__ d1, u16* __restrict__ d2) {
  __shared__ float s[64 * 65];
  const int bid = blockIdx.x;
  const int t = threadIdx.x;
  if (bid < 4096) {
    const int bx = bid & 63, by = (bid >> 6) & 3, z = bid >> 8;
    const float* src = z < 8 ? x : srcp;
    u16* dst = z < 8 ? cat : ssb;
    const int dstride = z < 8 ? 512 : 256;
    const int b = z & 7;
    const int lt = bx * 64, ct = by * 64;
    const int cl = t >> 2, loff = (t & 3) * 16;
#pragma unroll
    for (int j = 0; j < 4; ++j) {
      float4 v = *reinterpret_cast<const float4*>(
          src + ((size_t)b * 256 + ct + cl) * 4096 + lt + loff + j * 4);
      s[cl * 65 + loff + j * 4 + 0] = v.x;
      s[cl * 65 + loff + j * 4 + 1] = v.y;
      s[cl * 65 + loff + j * 4 + 2] = v.z;
      s[cl * 65 + loff + j * 4 + 3] = v.w;
    }
    __syncthreads();
#pragma unroll
    for (int i = 0; i < 2; ++i) {
      int id = t + i * 256;          // 0..511
      int ll = id >> 3, cg = id & 7;
      unsigned pk[4];
#pragma unroll
      for (int j = 0; j < 4; ++j) {
        unsigned lo = f2bf(s[(cg * 8 + j * 2) * 65 + ll]);
        unsigned hi = f2bf(s[(cg * 8 + j * 2 + 1) * 65 + ll]);
        pk[j] = lo | (hi << 16);
      }
      uint4 val = {pk[0], pk[1], pk[2], pk[3]};
      *reinterpret_cast<uint4*>(
          dst + ((size_t)b * 4096 + lt + ll) * dstride + ct + cg * 8) = val;
    }
  } else {
    const int wb = bid - 4096;
    const float* src; u16* dst; int Kd, Nd, tt;
    if (wb < 64)       { src = Wq; dst = dq; Kd = 256; Nd = 256; tt = wb; }
    else if (wb < 128) { src = Wk; dst = dk; Kd = 256; Nd = 256; tt = wb - 64; }
    else if (wb < 192) { src = Wv; dst = dv; Kd = 256; Nd = 256; tt = wb - 128; }
    else if (wb < 256) { src = Wm; dst = dm; Kd = 256; Nd = 256; tt = wb - 192; }
    else if (wb < 512) { src = W1; dst = d1; Kd = 512; Nd = 512; tt = wb - 256; }
    else               { src = W2; dst = d2; Kd = 512; Nd = 256; tt = wb - 512; }
    int ntn = Nd >> 5;
    int kt = (tt / ntn) * 32, nt = (tt % ntn) * 32;
    int tx = t & 31, ty = t >> 5;
#pragma unroll
    for (int i = 0; i < 4; ++i)
      s[(ty + i * 8) * 33 + tx] = src[(size_t)(kt + ty + i * 8) * Nd + nt + tx];
    __syncthreads();
#pragma unroll
    for (int i = 0; i < 4; ++i)
      dst[(size_t)(nt + ty + i * 8) * Kd + kt + tx] = f2bf(s[tx * 33 + ty + i * 8]);
  }
}

// ---- bf16 MFMA GEMM, 128x256 tile, 8 waves (2m x 4n), gload_lds staging -----
// Grid 512 linear. MAP=0: m-chunked per XCD (2 n-tiles/panel same XCD).
// MAP=1: panel p -> XCD p%8 (aligns with default round-robin of producer/
//        consumer kernels), n-tile pair kept on same XCD.
// EPI: 3 relu bf16 | 4 fused kv bf16
template <int EPI, int MAP>
__global__ __launch_bounds__(512) void gemm256_kernel(
    const u16* __restrict__ A, int lda, const u16* __restrict__ Wt, int K,
    u16* __restrict__ outp, int ldo) {
  __shared__ alignas(16) u16 sA[128 * 64];
  __shared__ alignas(16) u16 sB[256 * 64];
  const int t = threadIdx.x;
  int bid = blockIdx.x;
  int m0, n0;
  if (MAP == 0) {
    int xcd = bid & 7, i0 = bid >> 3;
    m0 = (xcd * 32 + (i0 >> 1)) * 128;
    n0 = (i0 & 1) * 256;
  } else {
    int xcd = bid & 7, j = bid >> 3;
    m0 = ((j >> 1) * 8 + xcd) * 128;   // panel p = (j>>1)*8+xcd -> XCD p%8
    n0 = (j & 1) * 256;
  }
  const int w = t >> 6, lane = t & 63;
  const int wm = (w >> 2) * 64, wn = (w & 3) * 64;
  const int lr = lane & 15, lk = lane >> 4;
  f32x4 acc[4][4] = {};
  const int nkt = K >> 6;
  for (int kt = 0; kt < nkt; ++kt) {
    __syncthreads();
#pragma unroll
    for (int i = 0; i < 2; ++i) {
      int id = t + i * 512, row = id >> 3, ch = (id & 7) << 3;
      GLDS16(A + (size_t)(m0 + row) * lda + kt * 64 + ch, sA + id * 8);
    }
#pragma unroll
    for (int i = 0; i < 4; ++i) {
      int id = t + i * 512, row = id >> 3, ch = (id & 7) << 3;
      GLDS16(Wt + (size_t)(n0 + row) * K + kt * 64 + ch, sB + id * 8);
    }
    __syncthreads();
    bf16x8 af[4][2], bfr[4][2];
#pragma unroll
    for (int f = 0; f < 4; ++f) {
#pragma unroll
      for (int ks = 0; ks < 2; ++ks) {
        af[f][ks] = *reinterpret_cast<const bf16x8*>(
            &sA[(wm + f * 16 + lr) * 64 + ks * 32 + lk * 8]);
        bfr[f][ks] = *reinterpret_cast<const bf16x8*>(
            &sB[(wn + f * 16 + lr) * 64 + ks * 32 + lk * 8]);
      }
    }
#pragma unroll
    for (int ks = 0; ks < 2; ++ks)
#pragma unroll
      for (int fm = 0; fm < 4; ++fm)
#pragma unroll
        for (int fn = 0; fn < 4; ++fn)
          acc[fm][fn] = __builtin_amdgcn_mfma_f32_16x16x32_bf16(
              af[fm][ks], bfr[fn][ks], acc[fm][fn], 0, 0, 0);
  }
  const int r0 = (lane >> 4) * 4, c0 = lane & 15;
#pragma unroll
  for (int fm = 0; fm < 4; ++fm) {
#pragma unroll
    for (int fn = 0; fn < 4; ++fn) {
      int gr = m0 + wm + fm * 16 + r0;
      int gc = n0 + wn + fn * 16 + c0;
#pragma unroll
      for (int r = 0; r < 4; ++r) {
        float v = acc[fm][fn][r];
        if (EPI == 3) v = v > 0.f ? v : 0.f;
        if (EPI == 4) v = (gc < 256) ? (v > 0.f ? v + 1.f : __expf(v)) : v * (1.f / 4096.f);
        outp[(size_t)(gr + r) * ldo + gc] = f2bf(v);
      }
    }
  }
}

// ---- KV partial over L-slices (reads bf16 kvproj [M][512]) ------------------
// flat grid 512, b = id&7 -> blocks for batch b land on XCD b, matching
// the kv-GEMM MAP=0 writes (panels 32b..32b+31 all written from XCD b).
__global__ __launch_bounds__(256) void kv_partial_kernel(
    const u16* __restrict__ KVproj, float* __restrict__ KVp,
    float* __restrict__ KSp) {
  __shared__ alignas(16) float sK[64][32];
  __shared__ alignas(16) float sV[64][32];
  const int id = blockIdx.x;
  const int b = id & 7, h = (id >> 3) & 7, sl = id >> 6;
  const int t = threadIdx.x;
  const int lrow = t >> 2, lcol = (t & 3) * 8;
  const int d = t >> 3, vg = (t & 7) * 4;
  float a0 = 0, a1 = 0, a2 = 0, a3 = 0, ks = 0;
  for (int lt = 0; lt < 512; lt += 64) {
    __syncthreads();
    size_t roff = ((size_t)b * 4096 + sl * 512 + lt + lrow) * 512 + h * 32 + lcol;
    uint4 kq = *reinterpret_cast<const uint4*>(KVproj + roff);
    uint4 vq = *reinterpret_cast<const uint4*>(KVproj + roff + 256);
    float* dk = &sK[lrow][lcol];
    float* dv = &sV[lrow][lcol];
#pragma unroll
    for (int j = 0; j < 4; ++j) {
      unsigned uk = ((const unsigned*)&kq)[j];
      unsigned uv = ((const unsigned*)&vq)[j];
      dk[2 * j] = __uint_as_float(uk << 16);
      dk[2 * j + 1] = __uint_as_float(uk & 0xffff0000u);
      dv[2 * j] = __uint_as_float(uv << 16);
      dv[2 * j + 1] = __uint_as_float(uv & 0xffff0000u);
    }
    __syncthreads();
#pragma unroll 8
    for (int i = 0; i < 64; ++i) {
      float kd = sK[i][d];
      a0 += kd * sV[i][vg + 0];
      a1 += kd * sV[i][vg + 1];
      a2 += kd * sV[i][vg + 2];
      a3 += kd * sV[i][vg + 3];
      ks += kd;
    }
  }
  const int bh = b * 8 + h;
  float* o = KVp + (size_t)sl * 65536 + bh * 1024 + d * 32 + vg;
  o[0] = a0; o[1] = a1; o[2] = a2; o[3] = a3;
  if ((t & 7) == 0) KSp[(size_t)sl * 2048 + bh * 32 + d] = ks;
}

// ---- merged: reduce KVp -> KV[b] (LDS) ; Ksum ; wcomb chunk -----------------
__global__ __launch_bounds__(256) void kvred_wcomb_kernel(
    const float* __restrict__ KVp, const float* __restrict__ KSp,
    const u16* __restrict__ wmt, u16* __restrict__ wc,
    float* __restrict__ Ksum) {
  __shared__ float sKV[8 * 1032];
  const int b = blockIdx.x >> 3, nc = blockIdx.x & 7;
  const int t = threadIdx.x;
#pragma unroll
  for (int i = 0; i < 32; ++i) {
    int idx = t + i * 256;
    float s = 0.f;
#pragma unroll
    for (int sl = 0; sl < 8; ++sl) s += KVp[(size_t)sl * 65536 + b * 8192 + idx];
    sKV[(idx >> 10) * 1032 + (idx & 1023)] = s;
  }
  if (nc == 0) {
    float s = 0.f;
#pragma unroll
    for (int sl = 0; sl < 8; ++sl) s += KSp[(size_t)sl * 2048 + b * 256 + t];
    Ksum[b * 256 + t] = s;
  }
  __syncthreads();
  const int n = nc * 32 + (t >> 3), h = t & 7;
  float wmv[32];
  const u16* wmrow = wmt + (size_t)n * 256 + h * 32;
#pragma unroll
  for (int v = 0; v < 32; ++v) wmv[v] = bf2f(wmrow[v]);
  unsigned pk[16];
  const float* kvh = &sKV[h * 1032];
#pragma unroll
  for (int dp = 0; dp < 16; ++dp) {
    unsigned lohi[2];
#pragma unroll
    for (int e = 0; e < 2; ++e) {
      int d = dp * 2 + e;
      const float* kv = kvh + d * 32;
      float s = 0.f;
#pragma unroll
      for (int v = 0; v < 32; ++v) s += kv[v] * wmv[v];
      lohi[e] = f2bf(s);
    }
    pk[dp] = lohi[0] | (lohi[1] << 16);
  }
  uint4* dst = (uint4*)(wc + ((size_t)b * 256 + n) * 256 + h * 32);
#pragma unroll
  for (int j = 0; j < 4; ++j) {
    uint4 val = {pk[j * 4], pk[j * 4 + 1], pk[j * 4 + 2], pk[j * 4 + 3]};
    dst[j] = val;
  }
}

// ---- FUSED: Qproj + elu+1 + z-scale + (Qs @ Wcomb) + LN1 -> cat[:,256:512] --
// BM=128, 512 threads (8 waves 2m x 4n), grid 256. (R8-proven form)
__global__ __launch_bounds__(512) void qmsg_kernel(
    const u16* __restrict__ cat, const u16* __restrict__ WqT,
    const float* __restrict__ KSb, const u16* __restrict__ wc,
    const float* __restrict__ g1, const float* __restrict__ b1,
    u16* __restrict__ catout) {
  __shared__ alignas(16) char smem[57344];
  u16* sA = (u16*)smem;
  u16* sB = (u16*)(smem + 16384);
  u16* Qlds = (u16*)smem;
  u16* sWc = (u16*)(smem + 35840);
  float* scr = (float*)(smem + 52224);
  const int t = threadIdx.x;
  const int m0 = blockIdx.x * 128;
  const int b = m0 >> 12;
  const int w = t >> 6, lane = t & 63;
  const int wm = (w >> 2) * 64, wn = (w & 3) * 64;
  const int lr = lane & 15, lk = lane >> 4;
  f32x4 acc[4][4] = {};
  float ksv[4];
#pragma unroll
  for (int fn = 0; fn < 4; ++fn) ksv[fn] = KSb[b * 256 + wn + fn * 16 + lr];
  // ---- phase 1: Q-proj GEMM (K=256) ----
  for (int kt = 0; kt < 4; ++kt) {
    __syncthreads();
#pragma unroll
    for (int i = 0; i < 2; ++i) {
      int id = t + i * 512, row = id >> 3, ch = (id & 7) << 3;
      GLDS16(cat + (size_t)(m0 + row) * 512 + kt * 64 + ch, sA + id * 8);
    }
#pragma unroll
    for (int i = 0; i < 4; ++i) {
      int id = t + i * 512, row = id >> 3, ch = (id & 7) << 3;
      GLDS16(WqT + (size_t)row * 256 + kt * 64 + ch, sB + id * 8);
    }
    __syncthreads();
    bf16x8 af[4][2], bfr[4][2];
#pragma unroll
    for (int f = 0; f < 4; ++f)
#pragma unroll
      for (int ks = 0; ks < 2; ++ks) {
        af[f][ks] = *(const bf16x8*)&sA[(wm + f * 16 + lr) * 64 + ks * 32 + lk * 8];
        bfr[f][ks] = *(const bf16x8*)&sB[(wn + f * 16 + lr) * 64 + ks * 32 + lk * 8];
      }
#pragma unroll
    for (int ks = 0; ks < 2; ++ks)
#pragma unroll
      for (int fm = 0; fm < 4; ++fm)
#pragma unroll
        for (int fn = 0; fn < 4; ++fn)
          acc[fm][fn] = __builtin_amdgcn_mfma_f32_16x16x32_bf16(
              af[fm][ks], bfr[fn][ks], acc[fm][fn], 0, 0, 0);
  }
  // ---- elu+1 and per-head z-scale ----
#pragma unroll
  for (int fm = 0; fm < 4; ++fm)
#pragma unroll
    for (int r = 0; r < 4; ++r) {
      float q[4];
#pragma unroll
      for (int fn = 0; fn < 4; ++fn) {
        float v = acc[fm][fn][r];
        q[fn] = v > 0.f ? v + 1.f : __expf(v);
      }
      float zd0 = q[0] * ksv[0] + q[1] * ksv[1];
      float zd1 = q[2] * ksv[2] + q[3] * ksv[3];
#pragma unroll
      for (int off = 1; off < 16; off <<= 1) {
        zd0 += __shfl_xor(zd0, off);
        zd1 += __shfl_xor(zd1, off);
      }
      float z0 = 4096.f / (zd0 + 1e-6f);
      float z1 = 4096.f / (zd1 + 1e-6f);
      acc[fm][0][r] = q[0] * z0; acc[fm][1][r] = q[1] * z0;
      acc[fm][2][r] = q[2] * z1; acc[fm][3][r] = q[3] * z1;
    }
  // ---- phase 2: msg = Qs @ Wcomb, two 128-col K-halves through Qlds --------
  f32x4 acc2[4][4] = {};
  const u16* Bw = wc + (size_t)b * 65536;
  for (int hh = 0; hh < 2; ++hh) {
    __syncthreads();                 // prior Qlds/sA/sB reads complete
    if ((wn >> 7) == hh) {
#pragma unroll
      for (int fm = 0; fm < 4; ++fm)
#pragma unroll
        for (int fn = 0; fn < 4; ++fn)
#pragma unroll
          for (int r = 0; r < 4; ++r)
            Qlds[(wm + fm * 16 + lk * 4 + r) * 136 + (wn & 64) + fn * 16 + lr] =
                f2bf(acc[fm][fn][r]);
    }
    __syncthreads();                 // Qlds visible
    for (int kc2 = 0; kc2 < 4; ++kc2) {
#pragma unroll
      for (int i = 0; i < 2; ++i) {
        int id = t + i * 512, row = id >> 2, ch = (id & 3) << 3;
        GLDS16(Bw + (size_t)row * 256 + hh * 128 + kc2 * 32 +
                   (ch ^ ((row & 3) << 3)), sWc + id * 8);
      }
      __syncthreads();               // sWc staged
      bf16x8 a2[4], b2f[4];
#pragma unroll
      for (int f = 0; f < 4; ++f)
        a2[f] = *(const bf16x8*)&Qlds[(wm + f * 16 + lr) * 136 + kc2 * 32 + lk * 8];
#pragma unroll
      for (int fn = 0; fn < 4; ++fn) {
        int br = wn + fn * 16 + lr;
        b2f[fn] = *(const bf16x8*)&sWc[br * 32 + ((lk * 8) ^ ((br & 3) << 3))];
      }
#pragma unroll
      for (int fm = 0; fm < 4; ++fm)
#pragma unroll
        for (int fn = 0; fn < 4; ++fn)
          acc2[fm][fn] = __builtin_amdgcn_mfma_f32_16x16x32_bf16(
              a2[fm], b2f[fn], acc2[fm][fn], 0, 0, 0);
      __syncthreads();               // frag reads done before sWc/Qlds overwrite
    }
  }
  // ---- LN1 cross-wave ----
#pragma unroll
  for (int fm = 0; fm < 4; ++fm)
#pragma unroll
    for (int r = 0; r < 4; ++r) {
      float s = 0.f, sq = 0.f;
#pragma unroll
      for (int fn = 0; fn < 4; ++fn) {
        float a = acc2[fm][fn][r];
        s += a; sq += a * a;
      }
#pragma unroll
      for (int off = 1; off < 16; off <<= 1) {
        s += __shfl_xor(s, off);
        sq += __shfl_xor(sq, off);
      }
      if (lr == 0) {
        int row = wm + fm * 16 + lk * 4 + r;
        scr[row * 8 + (w & 3) * 2] = s;
        scr[row * 8 + (w & 3) * 2 + 1] = sq;
      }
    }
  __syncthreads();
  float gvs[4], bvs[4];
#pragma unroll
  for (int fn = 0; fn < 4; ++fn) {
    gvs[fn] = g1[wn + fn * 16 + lr];
    bvs[fn] = b1[wn + fn * 16 + lr];
  }
#pragma unroll
  for (int fm = 0; fm < 4; ++fm)
#pragma unroll
    for (int r = 0; r < 4; ++r) {
      int row = wm + fm * 16 + lk * 4 + r;
      float s = 0.f, sq = 0.f;
#pragma unroll
      for (int j = 0; j < 4; ++j) {
        s += scr[row * 8 + j * 2];
        sq += scr[row * 8 + j * 2 + 1];
      }
      float mu = s * (1.f / 256.f);
      float var = sq * (1.f / 256.f) - mu * mu;
      float rstd = rsqrtf(var + 1e-5f);
#pragma unroll
      for (int fn = 0; fn < 4; ++fn) {
        float y = (acc2[fm][fn][r] - mu) * rstd * gvs[fn] + bvs[fn];
        catout[(size_t)(m0 + row) * 512 + 256 + wn + fn * 16 + lr] = f2bf(y);
      }
    }
}

// ---- FUSED: MLP2 + LN2 + bf16-residual + transpose -> out -------------------
__global__ __launch_bounds__(512) void mlp2_tail_kernel(
    const u16* __restrict__ hidden, const u16* __restrict__ W2T,
    const float* __restrict__ g2, const float* __restrict__ b2,
    const u16* __restrict__ catp, float* __restrict__ out) {
  __shared__ alignas(16) char smem[16384 + 32768 + 4096 + 2048];
  u16* sA = (u16*)smem;                   // [128][64]
  u16* sB = (u16*)(smem + 16384);         // [256][64]
  float* scr = (float*)(smem + 49152);    // [128][8]
  float* sG = (float*)(smem + 53248);     // g2|b2
  float* T = (float*)smem;                // [64][129] overlay, post-GEMM
  const int t = threadIdx.x;
  const int m0 = blockIdx.x * 128;
  const int b = m0 >> 12, l0 = m0 & 4095;
  if (t < 256) { sG[t] = g2[t]; sG[256 + t] = b2[t]; }
  const int w = t >> 6, lane = t & 63;
  const int wm = (w >> 2) * 64, wn = (w & 3) * 64;
  const int lr = lane & 15, lk = lane >> 4;
  f32x4 acc[4][4] = {};
  for (int kt = 0; kt < 8; ++kt) {
    __syncthreads();
#pragma unroll
    for (int i = 0; i < 2; ++i) {
      int id = t + i * 512, row = id >> 3, chn = (id & 7) << 3;
      GLDS16(hidden + (size_t)(m0 + row) * 512 + kt * 64 + chn, sA + id * 8);
    }
#pragma unroll
    for (int i = 0; i < 4; ++i) {
      int id = t + i * 512, row = id >> 3, chn = (id & 7) << 3;
      GLDS16(W2T + (size_t)row * 512 + kt * 64 + chn, sB + id * 8);
    }
    __syncthreads();
    bf16x8 af[4][2], bfr[4][2];
#pragma unroll
    for (int f = 0; f < 4; ++f) {
#pragma unroll
      for (int ks = 0; ks < 2; ++ks) {
        af[f][ks] = *reinterpret_cast<const bf16x8*>(
            &sA[(wm + f * 16 + lr) * 64 + ks * 32 + lk * 8]);
        bfr[f][ks] = *reinterpret_cast<const bf16x8*>(
            &sB[(wn + f * 16 + lr) * 64 + ks * 32 + lk * 8]);
      }
    }
#pragma unroll
    for (int ks = 0; ks < 2; ++ks)
#pragma unroll
      for (int fm = 0; fm < 4; ++fm)
#pragma unroll
        for (int fn = 0; fn < 4; ++fn)
          acc[fm][fn] = __builtin_amdgcn_mfma_f32_16x16x32_bf16(
              af[fm][ks], bfr[fn][ks], acc[fm][fn], 0, 0, 0);
  }
  // ---- LN2 cross-wave ----
#pragma unroll
  for (int fm = 0; fm < 4; ++fm)
#pragma unroll
    for (int r = 0; r < 4; ++r) {
      float s = 0.f, sq = 0.f;
#pragma unroll
      for (int fn = 0; fn < 4; ++fn) {
        float a = acc[fm][fn][r];
        s += a; sq += a * a;
      }
#pragma unroll
      for (int off = 1; off < 16; off <<= 1) {
        s += __shfl_xor(s, off);
        sq += __shfl_xor(sq, off);
      }
      if (lr == 0) {
        int row = wm + fm * 16 + lk * 4 + r;
        scr[row * 8 + (w & 3) * 2] = s;
        scr[row * 8 + (w & 3) * 2 + 1] = sq;
      }
    }
  __syncthreads();
  float gvs[4], bvs[4];
#pragma unroll
  for (int fn = 0; fn < 4; ++fn) {
    gvs[fn] = sG[wn + fn * 16 + lr];
    bvs[fn] = sG[256 + wn + fn * 16 + lr];
  }
#pragma unroll
  for (int fm = 0; fm < 4; ++fm)
#pragma unroll
    for (int r = 0; r < 4; ++r) {
      int row = wm + fm * 16 + lk * 4 + r;
      float s = 0.f, sq = 0.f;
#pragma unroll
      for (int j = 0; j < 4; ++j) {
        s += scr[row * 8 + j * 2];
        sq += scr[row * 8 + j * 2 + 1];
      }
      float mu = s * (1.f / 256.f);
      float var = sq * (1.f / 256.f) - mu * mu;
      float rstd = rsqrtf(var + 1e-5f);
#pragma unroll
      for (int fn = 0; fn < 4; ++fn) {
        float xs = bf2f(catp[(size_t)(m0 + row) * 512 + wn + fn * 16 + lr]);
        acc[fm][fn][r] = (acc[fm][fn][r] - mu) * rstd * gvs[fn] + bvs[fn] + xs;
      }
    }
  __syncthreads();
  // ---- transpose chunks of 64 cols, coalesced f32 write ----
  for (int cc = 0; cc < 4; ++cc) {
    if ((w & 3) == cc) {
#pragma unroll
      for (int fm = 0; fm < 4; ++fm)
#pragma unroll
        for (int fn = 0; fn < 4; ++fn)
#pragma unroll
          for (int r = 0; r < 4; ++r)
            T[(fn * 16 + lr) * 129 + wm + fm * 16 + lk * 4 + r] = acc[fm][fn][r];
    }
    __syncthreads();
#pragma unroll
    for (int i = 0; i < 4; ++i) {
      int idx = t + i * 512;
      int cT = idx >> 5, lq = (idx & 31) * 4;
      int cg = cc * 64 + cT;
      size_t o = ((size_t)b * 256 + cg) * 4096 + l0 + lq;
      float4 ov;
      ov.x = T[cT * 129 + lq];
      ov.y = T[cT * 129 + lq + 1];
      ov.z = T[cT * 129 + lq + 2];
      ov.w = T[cT * 129 + lq + 3];
      *reinterpret_cast<float4*>(out + o) = ov;
    }
    __syncthreads();
  }
}

extern "C" void kernel_launch(void* const* d_in, const int* in_sizes, int n_in,
                              void* d_out, int out_size, void* d_ws, size_t ws_size,
                              hipStream_t stream) {
  (void)in_sizes; (void)n_in; (void)out_size; (void)ws_size;
  const float* x = (const float*)d_in[0];
  const float* srcp = (const float*)d_in[1];
  const float* Wq = (const float*)d_in[2];
  const float* Wk = (const float*)d_in[3];
  const float* Wv = (const float*)d_in[4];
  const float* Wm = (const float*)d_in[5];
  const float* W1 = (const float*)d_in[6];
  const float* W2 = (const float*)d_in[7];
  const float* g1 = (const float*)d_in[8];
  const float* b1 = (const float*)d_in[9];
  const float* g2 = (const float*)d_in[10];
  const float* b2 = (const float*)d_in[11];
  float* out = (float*)d_out;
  char* ws = (char*)d_ws;

  u16* wqt = (u16*)(ws + OFF_WQ);
  u16* wkvt = (u16*)(ws + OFF_WK);
  u16* wkt = (u16*)(ws + OFF_WK);
  u16* wvt = (u16*)(ws + OFF_WV);
  u16* wmt = (u16*)(ws + OFF_WM);
  u16* w1t = (u16*)(ws + OFF_W1);
  u16* w2t = (u16*)(ws + OFF_W2);
  u16* cat = (u16*)(ws + OFF_CAT);
  u16* ssb = (u16*)(ws + OFF_SSB);
  u16* kvproj = (u16*)(ws + OFF_KVPROJ);
  float* KSb = (float*)(ws + OFF_KS);
  float* KVp = (float*)(ws + OFF_KVP);
  float* KSp = (float*)(ws + OFF_KSP);
  u16* wcombT = (u16*)(ws + OFF_WC);
  u16* hidden = kvproj;

  dim3 blk(256);
  prep_kernel<<<dim3(4736), blk, 0, stream>>>(x, srcp, cat, ssb,
                                              Wq, Wk, Wv, Wm, W1, W2,
                                              wqt, wkt, wvt, wmt, w1t, w2t);
  gemm256_kernel<4, 0><<<dim3(512), dim3(512), 0, stream>>>(ssb, 256, wkvt, 256, kvproj, 512);
  kv_partial_kernel<<<dim3(512), blk, 0, stream>>>(kvproj, KVp, KSp);
  kvred_wcomb_kernel<<<dim3(64), blk, 0, stream>>>(KVp, KSp, wmt, wcombT, KSb);
  qmsg_kernel<<<dim3(256), dim3(512), 0, stream>>>(cat, wqt, KSb, wcombT, g1, b1, cat);
  gemm256_kernel<3, 1><<<dim3(512), dim3(512), 0, stream>>>(cat, 512, w1t, 512, hidden, 512);
  mlp2_tail_kernel<<<dim3(256), dim3(512), 0, stream>>>(hidden, w2t, g2, b2, cat, out);
}

// Round 15
// 150.845 us; speedup vs baseline: 1.0670x; 1.0187x over previous
//
#include <hip/hip_runtime.h>

typedef unsigned short u16;
typedef __bf16 bf16x8 __attribute__((ext_vector_type(8)));
typedef float f32x4 __attribute__((ext_vector_type(4)));

__device__ __forceinline__ u16 f2bf(float f) {
  unsigned int u = __float_as_uint(f);
  u += 0x7fffu + ((u >> 16) & 1u);
  return (u16)(u >> 16);
}
__device__ __forceinline__ float bf2f(u16 v) {
  return __uint_as_float(((unsigned)v) << 16);
}

#define GLDS16(gp, lp)                                                   \
  __builtin_amdgcn_global_load_lds(                                      \
      (const __attribute__((address_space(1))) unsigned int*)(gp),       \
      (__attribute__((address_space(3))) unsigned int*)(lp), 16, 0, 0)

// byte-offset XOR swizzle within a 128B row (both-sides, rule #21)
#define SWZ(row, colb) ((colb) ^ (((row) & 7) << 4))

// B=8, C=256, L=4096, M=32768, NHEAD=8, dim=32
#define OFF_WQ     0u
#define OFF_WK     131072u
#define OFF_WV     262144u
#define OFF_WM     393216u
#define OFF_W1     524288u
#define OFF_W2     1048576u
#define OFF_CAT    1310720u
#define OFF_SSB    34865152u
#define OFF_KVPROJ 68419584u
#define OFF_KS     152567808u
#define OFF_KVP    152576000u
#define OFF_KSP    154673152u
#define OFF_WC     154740736u

// ---- merged prep: input transposes + weight prep ---------------------------
__global__ __launch_bounds__(256) void prep_kernel(
    const float* __restrict__ x, const float* __restrict__ srcp,
    u16* __restrict__ cat, u16* __restrict__ ssb,
    const float* __restrict__ Wq, const float* __restrict__ Wk,
    const float* __restrict__ Wv, const float* __restrict__ Wm,
    const float* __restrict__ W1, const float* __restrict__ W2,
    u16* __restrict__ dq, u16* __restrict__ dk, u16* __restrict__ dv,
    u16* __restrict__ dm, u16* __restrict__ d1, u16* __restrict__ d2) {
  __shared__ float s[64 * 65];
  const int bid = blockIdx.x;
  const int t = threadIdx.x;
  if (bid < 4096) {
    const int bx = bid & 63, by = (bid >> 6) & 3, z = bid >> 8;
    const float* src = z < 8 ? x : srcp;
    u16* dst = z < 8 ? cat : ssb;
    const int dstride = z < 8 ? 512 : 256;
    const int b = z & 7;
    const int lt = bx * 64, ct = by * 64;
    const int cl = t >> 2, loff = (t & 3) * 16;
#pragma unroll
    for (int j = 0; j < 4; ++j) {
      float4 v = *reinterpret_cast<const float4*>(
          src + ((size_t)b * 256 + ct + cl) * 4096 + lt + loff + j * 4);
      s[cl * 65 + loff + j * 4 + 0] = v.x;
      s[cl * 65 + loff + j * 4 + 1] = v.y;
      s[cl * 65 + loff + j * 4 + 2] = v.z;
      s[cl * 65 + loff + j * 4 + 3] = v.w;
    }
    __syncthreads();
#pragma unroll
    for (int i = 0; i < 2; ++i) {
      int id = t + i * 256;
      int ll = id >> 3, cg = id & 7;
      unsigned pk[4];
#pragma unroll
      for (int j = 0; j < 4; ++j) {
        unsigned lo = f2bf(s[(cg * 8 + j * 2) * 65 + ll]);
        unsigned hi = f2bf(s[(cg * 8 + j * 2 + 1) * 65 + ll]);
        pk[j] = lo | (hi << 16);
      }
      uint4 val = {pk[0], pk[1], pk[2], pk[3]};
      *reinterpret_cast<uint4*>(
          dst + ((size_t)b * 4096 + lt + ll) * dstride + ct + cg * 8) = val;
    }
  } else {
    const int wb = bid - 4096;
    const float* src; u16* dst; int Kd, Nd, tt;
    if (wb < 64)       { src = Wq; dst = dq; Kd = 256; Nd = 256; tt = wb; }
    else if (wb < 128) { src = Wk; dst = dk; Kd = 256; Nd = 256; tt = wb - 64; }
    else if (wb < 192) { src = Wv; dst = dv; Kd = 256; Nd = 256; tt = wb - 128; }
    else if (wb < 256) { src = Wm; dst = dm; Kd = 256; Nd = 256; tt = wb - 192; }
    else if (wb < 512) { src = W1; dst = d1; Kd = 512; Nd = 512; tt = wb - 256; }
    else               { src = W2; dst = d2; Kd = 512; Nd = 256; tt = wb - 512; }
    int ntn = Nd >> 5;
    int kt = (tt / ntn) * 32, nt = (tt % ntn) * 32;
    int tx = t & 31, ty = t >> 5;
#pragma unroll
    for (int i = 0; i < 4; ++i)
      s[(ty + i * 8) * 33 + tx] = src[(size_t)(kt + ty + i * 8) * Nd + nt + tx];
    __syncthreads();
#pragma unroll
    for (int i = 0; i < 4; ++i)
      dst[(size_t)(nt + ty + i * 8) * Kd + kt + tx] = f2bf(s[tx * 33 + ty + i * 8]);
  }
}

// ---- bf16 MFMA GEMM, 128x256 tile, 8 waves, 2-barrier (kv projection) ------
template <int EPI>
__global__ __launch_bounds__(512) void gemm256_kernel(
    const u16* __restrict__ A, int lda, const u16* __restrict__ Wt, int K,
    u16* __restrict__ outp, int ldo) {
  __shared__ alignas(16) u16 sA[128 * 64];
  __shared__ alignas(16) u16 sB[256 * 64];
  const int t = threadIdx.x;
  int bid = blockIdx.x;
  int xcd = bid & 7, i0 = bid >> 3;
  const int m0 = (xcd * 32 + (i0 >> 1)) * 128;
  const int n0 = (i0 & 1) * 256;
  const int w = t >> 6, lane = t & 63;
  const int wm = (w >> 2) * 64, wn = (w & 3) * 64;
  const int lr = lane & 15, lk = lane >> 4;
  f32x4 acc[4][4] = {};
  const int nkt = K >> 6;
  for (int kt = 0; kt < nkt; ++kt) {
    __syncthreads();
#pragma unroll
    for (int i = 0; i < 2; ++i) {
      int id = t + i * 512, row = id >> 3, ch = (id & 7) << 3;
      GLDS16(A + (size_t)(m0 + row) * lda + kt * 64 + ch, sA + id * 8);
    }
#pragma unroll
    for (int i = 0; i < 4; ++i) {
      int id = t + i * 512, row = id >> 3, ch = (id & 7) << 3;
      GLDS16(Wt + (size_t)(n0 + row) * K + kt * 64 + ch, sB + id * 8);
    }
    __syncthreads();
    bf16x8 af[4][2], bfr[4][2];
#pragma unroll
    for (int f = 0; f < 4; ++f) {
#pragma unroll
      for (int ks = 0; ks < 2; ++ks) {
        af[f][ks] = *reinterpret_cast<const bf16x8*>(
            &sA[(wm + f * 16 + lr) * 64 + ks * 32 + lk * 8]);
        bfr[f][ks] = *reinterpret_cast<const bf16x8*>(
            &sB[(wn + f * 16 + lr) * 64 + ks * 32 + lk * 8]);
      }
    }
#pragma unroll
    for (int ks = 0; ks < 2; ++ks)
#pragma unroll
      for (int fm = 0; fm < 4; ++fm)
#pragma unroll
        for (int fn = 0; fn < 4; ++fn)
          acc[fm][fn] = __builtin_amdgcn_mfma_f32_16x16x32_bf16(
              af[fm][ks], bfr[fn][ks], acc[fm][fn], 0, 0, 0);
  }
  const int r0 = (lane >> 4) * 4, c0 = lane & 15;
#pragma unroll
  for (int fm = 0; fm < 4; ++fm) {
#pragma unroll
    for (int fn = 0; fn < 4; ++fn) {
      int gr = m0 + wm + fm * 16 + r0;
      int gc = n0 + wn + fn * 16 + c0;
#pragma unroll
      for (int r = 0; r < 4; ++r) {
        float v = acc[fm][fn][r];
        if (EPI == 4) v = (gc < 256) ? (v > 0.f ? v + 1.f : __expf(v)) : v * (1.f / 4096.f);
        outp[(size_t)(gr + r) * ldo + gc] = f2bf(v);
      }
    }
  }
}

// ---- MLP1: 8-phase counted-vmcnt GEMM, 256x256 tile, BK=64, relu->bf16 -----
// 8 waves, each = 256 rows x 32 cols. LDS 128KB dynamic:
//   A[db][h]: db*32768 + h*16384 ; B[db][h]: 65536 + db*32768 + h*16384
// Phase p (0..7): tile = p<4 ? e : o ; A-half = (p>>1)&1 ; ks = p&1.
// Stage ledger (verified): p0:Ahi(o) p1:Blo(o) p2:Alo(e+2) p3:Bhi(o)+vmcnt0
//   p4:Blo(e+2) p5:Bhi(e+2) p6:Ahi(e+2) p7:Alo(o+2)+vmcnt2
__global__ __launch_bounds__(512, 1) void mlp1_8ph_kernel(
    const u16* __restrict__ A, const u16* __restrict__ Bw,
    u16* __restrict__ outp) {
  extern __shared__ char smem[];
  const int t = threadIdx.x;
  int bid = blockIdx.x;                // 256 blocks
  int xcd = bid & 7, i0 = bid >> 3;    // 32 per xcd
  const int m0 = (xcd * 16 + (i0 >> 1)) * 256;
  const int n0 = (i0 & 1) * 256;
  const int w = t >> 6, lane = t & 63;
  const int wn2 = w * 32;
  const int lr = lane & 15, lk = lane >> 4;
  f32x4 acc[16][2] = {};

#define STAGE_A(db, h, kt)                                                  \
  {                                                                         \
    _Pragma("unroll") for (int i_ = 0; i_ < 2; ++i_) {                      \
      int id_ = t + i_ * 512;                                               \
      int row_ = id_ >> 3, colb_ = (id_ & 7) * 16;                          \
      GLDS16(A + (size_t)(m0 + (h) * 128 + row_) * 512 + (kt) * 64 +        \
                 (SWZ(row_, colb_) >> 1),                                   \
             smem + (db) * 32768 + (h) * 16384 + id_ * 16);                 \
    }                                                                       \
  }
#define STAGE_B(db, h, kt)                                                  \
  {                                                                         \
    _Pragma("unroll") for (int i_ = 0; i_ < 2; ++i_) {                      \
      int id_ = t + i_ * 512;                                               \
      int row_ = id_ >> 3, colb_ = (id_ & 7) * 16;                          \
      GLDS16(Bw + (size_t)(n0 + (h) * 128 + row_) * 512 + (kt) * 64 +       \
                 (SWZ(row_, colb_) >> 1),                                   \
             smem + 65536 + (db) * 32768 + (h) * 16384 + id_ * 16);         \
    }                                                                       \
  }

  // prologue: tile0 (4 halves) + Alo(1); drain; barrier
  STAGE_A(0, 0, 0); STAGE_A(0, 1, 0); STAGE_B(0, 0, 0); STAGE_B(0, 1, 0);
  STAGE_A(1, 0, 1);
  asm volatile("s_waitcnt vmcnt(0)" ::: "memory");
  __builtin_amdgcn_s_barrier();

  for (int it = 0; it < 4; ++it) {
    const int e = 2 * it, o = e + 1;
#pragma unroll
    for (int p = 0; p < 8; ++p) {
      const int db = p >> 2;
      const int ah = (p >> 1) & 1;
      const int ks = p & 1;
      // ds-load register subtile: 8 A-frags + 2 B-frags
      bf16x8 af[8], bf[2];
#pragma unroll
      for (int j = 0; j < 8; ++j) {
        int mf = ah * 8 + j;
        int rowh = (mf & 7) * 16 + lr;
        af[j] = *(const bf16x8*)(smem + db * 32768 + (mf >> 3) * 16384 +
                                 rowh * 128 + SWZ(rowh, ks * 64 + lk * 16));
      }
#pragma unroll
      for (int fn = 0; fn < 2; ++fn) {
        int col = wn2 + fn * 16 + lr;
        int rowh = col & 127;
        bf[fn] = *(const bf16x8*)(smem + 65536 + db * 32768 +
                                  (col >> 7) * 16384 + rowh * 128 +
                                  SWZ(rowh, ks * 64 + lk * 16));
      }
      // stage per ledger
      if (p == 0) STAGE_A(1, 1, o)
      else if (p == 1) STAGE_B(1, 0, o)
      else if (p == 2) { if (e + 2 < 8) STAGE_A(0, 0, e + 2) }
      else if (p == 3) STAGE_B(1, 1, o)
      else if (p == 4) { if (e + 2 < 8) STAGE_B(0, 0, e + 2) }
      else if (p == 5) { if (e + 2 < 8) STAGE_B(0, 1, e + 2) }
      else if (p == 6) { if (e + 2 < 8) STAGE_A(0, 1, e + 2) }
      else             { if (o + 2 < 8) STAGE_A(1, 0, o + 2) }
      __builtin_amdgcn_s_barrier();
      asm volatile("s_waitcnt lgkmcnt(0)" ::: "memory");
      __builtin_amdgcn_sched_barrier(0);
      __builtin_amdgcn_s_setprio(1);
#pragma unroll
      for (int j = 0; j < 8; ++j)
#pragma unroll
        for (int fn = 0; fn < 2; ++fn)
          acc[ah * 8 + j][fn] = __builtin_amdgcn_mfma_f32_16x16x32_bf16(
              af[j], bf[fn], acc[ah * 8 + j][fn], 0, 0, 0);
      __builtin_amdgcn_s_setprio(0);
      if (p == 3) asm volatile("s_waitcnt vmcnt(0)" ::: "memory");
      if (p == 7) asm volatile("s_waitcnt vmcnt(2)" ::: "memory");
      __builtin_amdgcn_s_barrier();
    }
  }
  // epilogue: relu -> bf16
  const int r0 = (lane >> 4) * 4, c0 = lane & 15;
#pragma unroll
  for (int mf = 0; mf < 16; ++mf)
#pragma unroll
    for (int fn = 0; fn < 2; ++fn) {
      int gr = m0 + mf * 16 + r0;
      int gc = n0 + wn2 + fn * 16 + c0;
#pragma unroll
      for (int r = 0; r < 4; ++r) {
        float v = acc[mf][fn][r];
        outp[(size_t)(gr + r) * 512 + gc] = f2bf(v > 0.f ? v : 0.f);
      }
    }
#undef STAGE_A
#undef STAGE_B
}

// ---- KV partial over L-slices ----------------------------------------------
__global__ __launch_bounds__(256) void kv_partial_kernel(
    const u16* __restrict__ KVproj, float* __restrict__ KVp,
    float* __restrict__ KSp) {
  __shared__ alignas(16) float sK[64][32];
  __shared__ alignas(16) float sV[64][32];
  const int id = blockIdx.x;
  const int b = id & 7, h = (id >> 3) & 7, sl = id >> 6;
  const int t = threadIdx.x;
  const int lrow = t >> 2, lcol = (t & 3) * 8;
  const int d = t >> 3, vg = (t & 7) * 4;
  float a0 = 0, a1 = 0, a2 = 0, a3 = 0, ks = 0;
  for (int lt = 0; lt < 512; lt += 64) {
    __syncthreads();
    size_t roff = ((size_t)b * 4096 + sl * 512 + lt + lrow) * 512 + h * 32 + lcol;
    uint4 kq = *reinterpret_cast<const uint4*>(KVproj + roff);
    uint4 vq = *reinterpret_cast<const uint4*>(KVproj + roff + 256);
    float* dk = &sK[lrow][lcol];
    float* dv = &sV[lrow][lcol];
#pragma unroll
    for (int j = 0; j < 4; ++j) {
      unsigned uk = ((const unsigned*)&kq)[j];
      unsigned uv = ((const unsigned*)&vq)[j];
      dk[2 * j] = __uint_as_float(uk << 16);
      dk[2 * j + 1] = __uint_as_float(uk & 0xffff0000u);
      dv[2 * j] = __uint_as_float(uv << 16);
      dv[2 * j + 1] = __uint_as_float(uv & 0xffff0000u);
    }
    __syncthreads();
#pragma unroll 8
    for (int i = 0; i < 64; ++i) {
      float kd = sK[i][d];
      a0 += kd * sV[i][vg + 0];
      a1 += kd * sV[i][vg + 1];
      a2 += kd * sV[i][vg + 2];
      a3 += kd * sV[i][vg + 3];
      ks += kd;
    }
  }
  const int bh = b * 8 + h;
  float* o = KVp + (size_t)sl * 65536 + bh * 1024 + d * 32 + vg;
  o[0] = a0; o[1] = a1; o[2] = a2; o[3] = a3;
  if ((t & 7) == 0) KSp[(size_t)sl * 2048 + bh * 32 + d] = ks;
}

// ---- merged: reduce KVp -> KV[b]; Ksum; wcomb chunk ------------------------
__global__ __launch_bounds__(256) void kvred_wcomb_kernel(
    const float* __restrict__ KVp, const float* __restrict__ KSp,
    const u16* __restrict__ wmt, u16* __restrict__ wc,
    float* __restrict__ Ksum) {
  __shared__ float sKV[8 * 1032];
  const int b = blockIdx.x >> 3, nc = blockIdx.x & 7;
  const int t = threadIdx.x;
#pragma unroll
  for (int i = 0; i < 32; ++i) {
    int idx = t + i * 256;
    float s = 0.f;
#pragma unroll
    for (int sl = 0; sl < 8; ++sl) s += KVp[(size_t)sl * 65536 + b * 8192 + idx];
    sKV[(idx >> 10) * 1032 + (idx & 1023)] = s;
  }
  if (nc == 0) {
    float s = 0.f;
#pragma unroll
    for (int sl = 0; sl < 8; ++sl) s += KSp[(size_t)sl * 2048 + b * 256 + t];
    Ksum[b * 256 + t] = s;
  }
  __syncthreads();
  const int n = nc * 32 + (t >> 3), h = t & 7;
  float wmv[32];
  const u16* wmrow = wmt + (size_t)n * 256 + h * 32;
#pragma unroll
  for (int v = 0; v < 32; ++v) wmv[v] = bf2f(wmrow[v]);
  unsigned pk[16];
  const float* kvh = &sKV[h * 1032];
#pragma unroll
  for (int dp = 0; dp < 16; ++dp) {
    unsigned lohi[2];
#pragma unroll
    for (int e = 0; e < 2; ++e) {
      int d = dp * 2 + e;
      const float* kv = kvh + d * 32;
      float s = 0.f;
#pragma unroll
      for (int v = 0; v < 32; ++v) s += kv[v] * wmv[v];
      lohi[e] = f2bf(s);
    }
    pk[dp] = lohi[0] | (lohi[1] << 16);
  }
  uint4* dst = (uint4*)(wc + ((size_t)b * 256 + n) * 256 + h * 32);
#pragma unroll
  for (int j = 0; j < 4; ++j) {
    uint4 val = {pk[j * 4], pk[j * 4 + 1], pk[j * 4 + 2], pk[j * 4 + 3]};
    dst[j] = val;
  }
}

// ---- FUSED: Qproj + elu+1 + z-scale + (Qs @ Wcomb) + LN1 -------------------
__global__ __launch_bounds__(512) void qmsg_kernel(
    const u16* __restrict__ cat, const u16* __restrict__ WqT,
    const float* __restrict__ KSb, const u16* __restrict__ wc,
    const float* __restrict__ g1, const float* __restrict__ b1,
    u16* __restrict__ catout) {
  __shared__ alignas(16) char smem[57344];
  u16* sA = (u16*)smem;
  u16* sB = (u16*)(smem + 16384);
  u16* Qlds = (u16*)smem;
  u16* sWc = (u16*)(smem + 35840);
  float* scr = (float*)(smem + 52224);
  const int t = threadIdx.x;
  const int m0 = blockIdx.x * 128;
  const int b = m0 >> 12;
  const int w = t >> 6, lane = t & 63;
  const int wm = (w >> 2) * 64, wn = (w & 3) * 64;
  const int lr = lane & 15, lk = lane >> 4;
  f32x4 acc[4][4] = {};
  float ksv[4];
#pragma unroll
  for (int fn = 0; fn < 4; ++fn) ksv[fn] = KSb[b * 256 + wn + fn * 16 + lr];
  for (int kt = 0; kt < 4; ++kt) {
    __syncthreads();
#pragma unroll
    for (int i = 0; i < 2; ++i) {
      int id = t + i * 512, row = id >> 3, ch = (id & 7) << 3;
      GLDS16(cat + (size_t)(m0 + row) * 512 + kt * 64 + ch, sA + id * 8);
    }
#pragma unroll
    for (int i = 0; i < 4; ++i) {
      int id = t + i * 512, row = id >> 3, ch = (id & 7) << 3;
      GLDS16(WqT + (size_t)row * 256 + kt * 64 + ch, sB + id * 8);
    }
    __syncthreads();
    bf16x8 af[4][2], bfr[4][2];
#pragma unroll
    for (int f = 0; f < 4; ++f)
#pragma unroll
      for (int ks = 0; ks < 2; ++ks) {
        af[f][ks] = *(const bf16x8*)&sA[(wm + f * 16 + lr) * 64 + ks * 32 + lk * 8];
        bfr[f][ks] = *(const bf16x8*)&sB[(wn + f * 16 + lr) * 64 + ks * 32 + lk * 8];
      }
#pragma unroll
    for (int ks = 0; ks < 2; ++ks)
#pragma unroll
      for (int fm = 0; fm < 4; ++fm)
#pragma unroll
        for (int fn = 0; fn < 4; ++fn)
          acc[fm][fn] = __builtin_amdgcn_mfma_f32_16x16x32_bf16(
              af[fm][ks], bfr[fn][ks], acc[fm][fn], 0, 0, 0);
  }
#pragma unroll
  for (int fm = 0; fm < 4; ++fm)
#pragma unroll
    for (int r = 0; r < 4; ++r) {
      float q[4];
#pragma unroll
      for (int fn = 0; fn < 4; ++fn) {
        float v = acc[fm][fn][r];
        q[fn] = v > 0.f ? v + 1.f : __expf(v);
      }
      float zd0 = q[0] * ksv[0] + q[1] * ksv[1];
      float zd1 = q[2] * ksv[2] + q[3] * ksv[3];
#pragma unroll
      for (int off = 1; off < 16; off <<= 1) {
        zd0 += __shfl_xor(zd0, off);
        zd1 += __shfl_xor(zd1, off);
      }
      float z0 = 4096.f / (zd0 + 1e-6f);
      float z1 = 4096.f / (zd1 + 1e-6f);
      acc[fm][0][r] = q[0] * z0; acc[fm][1][r] = q[1] * z0;
      acc[fm][2][r] = q[2] * z1; acc[fm][3][r] = q[3] * z1;
    }
  f32x4 acc2[4][4] = {};
  const u16* Bw = wc + (size_t)b * 65536;
  for (int hh = 0; hh < 2; ++hh) {
    __syncthreads();
    if ((wn >> 7) == hh) {
#pragma unroll
      for (int fm = 0; fm < 4; ++fm)
#pragma unroll
        for (int fn = 0; fn < 4; ++fn)
#pragma unroll
          for (int r = 0; r < 4; ++r)
            Qlds[(wm + fm * 16 + lk * 4 + r) * 136 + (wn & 64) + fn * 16 + lr] =
                f2bf(acc[fm][fn][r]);
    }
    __syncthreads();
    for (int kc2 = 0; kc2 < 4; ++kc2) {
#pragma unroll
      for (int i = 0; i < 2; ++i) {
        int id = t + i * 512, row = id >> 2, ch = (id & 3) << 3;
        GLDS16(Bw + (size_t)row * 256 + hh * 128 + kc2 * 32 +
                   (ch ^ ((row & 3) << 3)), sWc + id * 8);
      }
      __syncthreads();
      bf16x8 a2[4], b2f[4];
#pragma unroll
      for (int f = 0; f < 4; ++f)
        a2[f] = *(const bf16x8*)&Qlds[(wm + f * 16 + lr) * 136 + kc2 * 32 + lk * 8];
#pragma unroll
      for (int fn = 0; fn < 4; ++fn) {
        int br = wn + fn * 16 + lr;
        b2f[fn] = *(const bf16x8*)&sWc[br * 32 + ((lk * 8) ^ ((br & 3) << 3))];
      }
#pragma unroll
      for (int fm = 0; fm < 4; ++fm)
#pragma unroll
        for (int fn = 0; fn < 4; ++fn)
          acc2[fm][fn] = __builtin_amdgcn_mfma_f32_16x16x32_bf16(
              a2[fm], b2f[fn], acc2[fm][fn], 0, 0, 0);
      __syncthreads();
    }
  }
#pragma unroll
  for (int fm = 0; fm < 4; ++fm)
#pragma unroll
    for (int r = 0; r < 4; ++r) {
      float s = 0.f, sq = 0.f;
#pragma unroll
      for (int fn = 0; fn < 4; ++fn) {
        float a = acc2[fm][fn][r];
        s += a; sq += a * a;
      }
#pragma unroll
      for (int off = 1; off < 16; off <<= 1) {
        s += __shfl_xor(s, off);
        sq += __shfl_xor(sq, off);
      }
      if (lr == 0) {
        int row = wm + fm * 16 + lk * 4 + r;
        scr[row * 8 + (w & 3) * 2] = s;
        scr[row * 8 + (w & 3) * 2 + 1] = sq;
      }
    }
  __syncthreads();
  float gvs[4], bvs[4];
#pragma unroll
  for (int fn = 0; fn < 4; ++fn) {
    gvs[fn] = g1[wn + fn * 16 + lr];
    bvs[fn] = b1[wn + fn * 16 + lr];
  }
#pragma unroll
  for (int fm = 0; fm < 4; ++fm)
#pragma unroll
    for (int r = 0; r < 4; ++r) {
      int row = wm + fm * 16 + lk * 4 + r;
      float s = 0.f, sq = 0.f;
#pragma unroll
      for (int j = 0; j < 4; ++j) {
        s += scr[row * 8 + j * 2];
        sq += scr[row * 8 + j * 2 + 1];
      }
      float mu = s * (1.f / 256.f);
      float var = sq * (1.f / 256.f) - mu * mu;
      float rstd = rsqrtf(var + 1e-5f);
#pragma unroll
      for (int fn = 0; fn < 4; ++fn) {
        float y = (acc2[fm][fn][r] - mu) * rstd * gvs[fn] + bvs[fn];
        catout[(size_t)(m0 + row) * 512 + 256 + wn + fn * 16 + lr] = f2bf(y);
      }
    }
}

// ---- FUSED: MLP2 + LN2 + bf16-residual + transpose -> out ------------------
__global__ __launch_bounds__(512) void mlp2_tail_kernel(
    const u16* __restrict__ hidden, const u16* __restrict__ W2T,
    const float* __restrict__ g2, const float* __restrict__ b2,
    const u16* __restrict__ catp, float* __restrict__ out) {
  __shared__ alignas(16) char smem[16384 + 32768 + 4096 + 2048];
  u16* sA = (u16*)smem;
  u16* sB = (u16*)(smem + 16384);
  float* scr = (float*)(smem + 49152);
  float* sG = (float*)(smem + 53248);
  float* T = (float*)smem;
  const int t = threadIdx.x;
  const int m0 = blockIdx.x * 128;
  const int b = m0 >> 12, l0 = m0 & 4095;
  if (t < 256) { sG[t] = g2[t]; sG[256 + t] = b2[t]; }
  const int w = t >> 6, lane = t & 63;
  const int wm = (w >> 2) * 64, wn = (w & 3) * 64;
  const int lr = lane & 15, lk = lane >> 4;
  f32x4 acc[4][4] = {};
  for (int kt = 0; kt < 8; ++kt) {
    __syncthreads();
#pragma unroll
    for (int i = 0; i < 2; ++i) {
      int id = t + i * 512, row = id >> 3, chn = (id & 7) << 3;
      GLDS16(hidden + (size_t)(m0 + row) * 512 + kt * 64 + chn, sA + id * 8);
    }
#pragma unroll
    for (int i = 0; i < 4; ++i) {
      int id = t + i * 512, row = id >> 3, chn = (id & 7) << 3;
      GLDS16(W2T + (size_t)row * 512 + kt * 64 + chn, sB + id * 8);
    }
    __syncthreads();
    bf16x8 af[4][2], bfr[4][2];
#pragma unroll
    for (int f = 0; f < 4; ++f) {
#pragma unroll
      for (int ks = 0; ks < 2; ++ks) {
        af[f][ks] = *reinterpret_cast<const bf16x8*>(
            &sA[(wm + f * 16 + lr) * 64 + ks * 32 + lk * 8]);
        bfr[f][ks] = *reinterpret_cast<const bf16x8*>(
            &sB[(wn + f * 16 + lr) * 64 + ks * 32 + lk * 8]);
      }
    }
#pragma unroll
    for (int ks = 0; ks < 2; ++ks)
#pragma unroll
      for (int fm = 0; fm < 4; ++fm)
#pragma unroll
        for (int fn = 0; fn < 4; ++fn)
          acc[fm][fn] = __builtin_amdgcn_mfma_f32_16x16x32_bf16(
              af[fm][ks], bfr[fn][ks], acc[fm][fn], 0, 0, 0);
  }
#pragma unroll
  for (int fm = 0; fm < 4; ++fm)
#pragma unroll
    for (int r = 0; r < 4; ++r) {
      float s = 0.f, sq = 0.f;
#pragma unroll
      for (int fn = 0; fn < 4; ++fn) {
        float a = acc[fm][fn][r];
        s += a; sq += a * a;
      }
#pragma unroll
      for (int off = 1; off < 16; off <<= 1) {
        s += __shfl_xor(s, off);
        sq += __shfl_xor(sq, off);
      }
      if (lr == 0) {
        int row = wm + fm * 16 + lk * 4 + r;
        scr[row * 8 + (w & 3) * 2] = s;
        scr[row * 8 + (w & 3) * 2 + 1] = sq;
      }
    }
  __syncthreads();
  float gvs[4], bvs[4];
#pragma unroll
  for (int fn = 0; fn < 4; ++fn) {
    gvs[fn] = sG[wn + fn * 16 + lr];
    bvs[fn] = sG[256 + wn + fn * 16 + lr];
  }
#pragma unroll
  for (int fm = 0; fm < 4; ++fm)
#pragma unroll
    for (int r = 0; r < 4; ++r) {
      int row = wm + fm * 16 + lk * 4 + r;
      float s = 0.f, sq = 0.f;
#pragma unroll
      for (int j = 0; j < 4; ++j) {
        s += scr[row * 8 + j * 2];
        sq += scr[row * 8 + j * 2 + 1];
      }
      float mu = s * (1.f / 256.f);
      float var = sq * (1.f / 256.f) - mu * mu;
      float rstd = rsqrtf(var + 1e-5f);
#pragma unroll
      for (int fn = 0; fn < 4; ++fn) {
        float xs = bf2f(catp[(size_t)(m0 + row) * 512 + wn + fn * 16 + lr]);
        acc[fm][fn][r] = (acc[fm][fn][r] - mu) * rstd * gvs[fn] + bvs[fn] + xs;
      }
    }
  __syncthreads();
  for (int cc = 0; cc < 4; ++cc) {
    if ((w & 3) == cc) {
#pragma unroll
      for (int fm = 0; fm < 4; ++fm)
#pragma unroll
        for (int fn = 0; fn < 4; ++fn)
#pragma unroll
          for (int r = 0; r < 4; ++r)
            T[(fn * 16 + lr) * 129 + wm + fm * 16 + lk * 4 + r] = acc[fm][fn][r];
    }
    __syncthreads();
#pragma unroll
    for (int i = 0; i < 4; ++i) {
      int idx = t + i * 512;
      int cT = idx >> 5, lq = (idx & 31) * 4;
      int cg = cc * 64 + cT;
      size_t o = ((size_t)b * 256 + cg) * 4096 + l0 + lq;
      float4 ov;
      ov.x = T[cT * 129 + lq];
      ov.y = T[cT * 129 + lq + 1];
      ov.z = T[cT * 129 + lq + 2];
      ov.w = T[cT * 129 + lq + 3];
      *reinterpret_cast<float4*>(out + o) = ov;
    }
    __syncthreads();
  }
}

extern "C" void kernel_launch(void* const* d_in, const int* in_sizes, int n_in,
                              void* d_out, int out_size, void* d_ws, size_t ws_size,
                              hipStream_t stream) {
  (void)in_sizes; (void)n_in; (void)out_size; (void)ws_size;
  const float* x = (const float*)d_in[0];
  const float* srcp = (const float*)d_in[1];
  const float* Wq = (const float*)d_in[2];
  const float* Wk = (const float*)d_in[3];
  const float* Wv = (const float*)d_in[4];
  const float* Wm = (const float*)d_in[5];
  const float* W1 = (const float*)d_in[6];
  const float* W2 = (const float*)d_in[7];
  const float* g1 = (const float*)d_in[8];
  const float* b1 = (const float*)d_in[9];
  const float* g2 = (const float*)d_in[10];
  const float* b2 = (const float*)d_in[11];
  float* out = (float*)d_out;
  char* ws = (char*)d_ws;

  u16* wqt = (u16*)(ws + OFF_WQ);
  u16* wkvt = (u16*)(ws + OFF_WK);
  u16* wkt = (u16*)(ws + OFF_WK);
  u16* wvt = (u16*)(ws + OFF_WV);
  u16* wmt = (u16*)(ws + OFF_WM);
  u16* w1t = (u16*)(ws + OFF_W1);
  u16* w2t = (u16*)(ws + OFF_W2);
  u16* cat = (u16*)(ws + OFF_CAT);
  u16* ssb = (u16*)(ws + OFF_SSB);
  u16* kvproj = (u16*)(ws + OFF_KVPROJ);
  float* KSb = (float*)(ws + OFF_KS);
  float* KVp = (float*)(ws + OFF_KVP);
  float* KSp = (float*)(ws + OFF_KSP);
  u16* wcombT = (u16*)(ws + OFF_WC);
  u16* hidden = kvproj;

  static bool attr_done = false;
  hipFuncSetAttribute((const void*)mlp1_8ph_kernel,
                      hipFuncAttributeMaxDynamicSharedMemorySize, 131072);
  (void)attr_done;

  dim3 blk(256);
  prep_kernel<<<dim3(4736), blk, 0, stream>>>(x, srcp, cat, ssb,
                                              Wq, Wk, Wv, Wm, W1, W2,
                                              wqt, wkt, wvt, wmt, w1t, w2t);
  gemm256_kernel<4><<<dim3(512), dim3(512), 0, stream>>>(ssb, 256, wkvt, 256, kvproj, 512);
  kv_partial_kernel<<<dim3(512), blk, 0, stream>>>(kvproj, KVp, KSp);
  kvred_wcomb_kernel<<<dim3(64), blk, 0, stream>>>(KVp, KSp, wmt, wcombT, KSb);
  qmsg_kernel<<<dim3(256), dim3(512), 0, stream>>>(cat, wqt, KSb, wcombT, g1, b1, cat);
  mlp1_8ph_kernel<<<dim3(256), dim3(512), 131072, stream>>>(cat, w1t, hidden);
  mlp2_tail_kernel<<<dim3(256), dim3(512), 0, stream>>>(hidden, w2t, g2, b2, cat, out);
}